// Round 13
// baseline (306.035 us; speedup 1.0000x reference)
//
#include <hip/hip_runtime.h>
#include <hip/hip_bf16.h>
#include <math.h>

// Transformer block (pre-LN attn + MLP), B=4 T=1024 H=1024 K=16 HD=64.
// R23: (1) mlp1 epilogue 4->2 passes (lc holds 128 rows, 67.6KB; halves
// barriers+store loops); (2) prep kernels (tcvt3 + 2x tcvt + pack_bias)
// fused into one 11276-block launch (kills 3 launch gaps); (3) XCD-aware
// bijective block swizzle on qkv/mlp1/mlp2 (each XCD owns whole B-panels,
// L2-resident: mlp1 2x2.1MB, mlp2 1MB; diagnostic = mlp1 FETCH 37GB->?).
// GEMM structure (session-validated R19-R22): counted-vmcnt phase loops;
// mlp1 256x256 8-phase; mlp2 128x128 4-phase no-split-K RMW; qkv 128x128
// 4-phase with Q/K/V scatter epilogue.
// Attention: fused flash-style, 64-row Q-tiles, separate lK/lV, 2 barriers
// per kt, K(kt+1) prefetch hidden under softmax, setprio on MFMA clusters;
// masked logits FILLED with 1e-9; fully-masked K-tiles contribute
// exp(1e-9-m)*suffixV analytically (TV precomputed).

typedef __attribute__((ext_vector_type(8))) short bf16x8;
typedef __attribute__((ext_vector_type(4))) float f32x4;

#define DEVINL __device__ __forceinline__

#define LOG2E_SCALE 0.18033688f      /* 0.125 * log2(e) */
#define MASK2 1.4426950408889634e-9f /* 1e-9 * log2(e) */

DEVINL void stage16(const __hip_bfloat16* g, short* l) {
  __builtin_amdgcn_global_load_lds(
      (const __attribute__((address_space(1))) unsigned int*)g,
      (__attribute__((address_space(3))) unsigned int*)l, 16, 0, 0);
}

DEVINL float bf2f(short u) {
  unsigned x = ((unsigned)(unsigned short)u) << 16;
  float f; __builtin_memcpy(&f, &x, 4); return f;
}

DEVINL short f2bf_s(float f) {
  __hip_bfloat16 h = __float2bfloat16(f);
  short s; __builtin_memcpy(&s, &h, 2); return s;
}

DEVINL float block_sum(float v, float* sb) {
  #pragma unroll
  for (int o = 32; o; o >>= 1) v += __shfl_down(v, o);
  const int lane = threadIdx.x & 63, w = threadIdx.x >> 6;
  if (lane == 0) sb[w] = v;
  __syncthreads();
  float r = sb[0] + sb[1] + sb[2] + sb[3];
  __syncthreads();
  return r;
}

// XCD-aware bijective block swizzle (nwg % 8 == 0): each XCD gets a
// contiguous wg range -> whole B-panels L2-resident.
DEVINL void xcd_swz(int& bx, int& by) {
  const int nx = gridDim.x, nwg = nx * gridDim.y;
  const int flat = blockIdx.y * nx + blockIdx.x;
  const int wg = (flat & 7) * (nwg >> 3) + (flat >> 3);
  bx = wg % nx; by = wg / nx;
}

// ======== shared phase-schedule helpers ========
DEVINL void ph_sync() {
  __builtin_amdgcn_s_barrier();
  asm volatile("s_waitcnt lgkmcnt(0)" ::: "memory");
  __builtin_amdgcn_sched_barrier(0);
}

// 8-MFMA phase (acc[4][2]; af = A-half MH, bf = 2 N-frags) — mlp2/qkv shape
template<int MH>
DEVINL void mmh(f32x4 (&acc)[4][2], bf16x8 (&af)[2][2], bf16x8 (&bf)[2][2]) {
  __builtin_amdgcn_s_setprio(1);
  #pragma unroll
  for (int mi2 = 0; mi2 < 2; mi2++)
    #pragma unroll
    for (int ni = 0; ni < 2; ni++)
      #pragma unroll
      for (int ks = 0; ks < 2; ks++)
        acc[MH * 2 + mi2][ni] = __builtin_amdgcn_mfma_f32_16x16x32_bf16(
            af[mi2][ks], bf[ni][ks], acc[MH * 2 + mi2][ni], 0, 0, 0);
  __builtin_amdgcn_s_setprio(0);
  __builtin_amdgcn_s_barrier();
}

// 16-MFMA phase for mlp1 (acc[8][4])
template<int MH, int NH>
DEVINL void ph_read(const short* pa, const short* pb, int wr, int wc,
                    int lr, int lq, bf16x8 (&af)[4][2], bf16x8 (&bf)[2][2]) {
  if (NH == 0) {
    #pragma unroll
    for (int mi2 = 0; mi2 < 4; mi2++)
      #pragma unroll
      for (int ks = 0; ks < 2; ks++) {
        const int r = wr * 128 + MH * 64 + mi2 * 16 + lr;
        af[mi2][ks] = *(const bf16x8*)(pa + r * 64 + (((ks * 4 + lq) ^ (r & 7)) << 3));
      }
  }
  #pragma unroll
  for (int ni2 = 0; ni2 < 2; ni2++)
    #pragma unroll
    for (int ks = 0; ks < 2; ks++) {
      const int n = wc * 64 + NH * 32 + ni2 * 16 + lr;
      bf[ni2][ks] = *(const bf16x8*)(pb + n * 64 + (((ks * 4 + lq) ^ (n & 7)) << 3));
    }
}

template<int MH, int NH>
DEVINL void ph_mfma(f32x4 (&acc)[8][4], bf16x8 (&af)[4][2], bf16x8 (&bf)[2][2]) {
  __builtin_amdgcn_s_setprio(1);
  #pragma unroll
  for (int mi2 = 0; mi2 < 4; mi2++)
    #pragma unroll
    for (int ni2 = 0; ni2 < 2; ni2++)
      #pragma unroll
      for (int ks = 0; ks < 2; ks++)
        acc[MH * 4 + mi2][NH * 2 + ni2] = __builtin_amdgcn_mfma_f32_16x16x32_bf16(
            af[mi2][ks], bf[ni2][ks], acc[MH * 4 + mi2][NH * 2 + ni2], 0, 0, 0);
  __builtin_amdgcn_s_setprio(0);
  __builtin_amdgcn_s_barrier();
}

// ---- fused prep: W transposes (f32->bf16) + bias pack, one launch ----
// blocks [0,3072): Wq/Wk/Wv -> wqkv; [3072,7168): W1 -> w1t;
// [7168,11264): W2 -> w2t; [11264,11276): pack bqkv.
__global__ __launch_bounds__(256) void k_prep(
    const float* __restrict__ Wq, const float* __restrict__ Wk,
    const float* __restrict__ Wv, __hip_bfloat16* __restrict__ wqkv,
    const float* __restrict__ W1, __hip_bfloat16* __restrict__ w1t,
    const float* __restrict__ W2, __hip_bfloat16* __restrict__ w2t,
    const float* __restrict__ bq, const float* __restrict__ bk,
    const float* __restrict__ bv, float* __restrict__ bqkv) {
  __shared__ float tile[32][33];
  const int bid = blockIdx.x;
  const int tx = threadIdx.x, ty = threadIdx.y;  // (32,8)
  const float* src; __hip_bfloat16* dst;
  int c0, r0, C, dOff, dPitch;
  if (bid < 3072) {
    const int z = bid >> 10, rem = bid & 1023;
    src = z == 0 ? Wq : (z == 1 ? Wk : Wv); dst = wqkv;
    c0 = (rem & 31) * 32; r0 = (rem >> 5) * 32;
    C = 1024; dOff = z << 10; dPitch = 1024;
  } else if (bid < 7168) {
    const int rem = bid - 3072;
    src = W1; dst = w1t;
    c0 = (rem & 127) * 32; r0 = (rem >> 7) * 32;
    C = 4096; dOff = 0; dPitch = 1024;
  } else if (bid < 11264) {
    const int rem = bid - 7168;
    src = W2; dst = w2t;
    c0 = (rem & 31) * 32; r0 = (rem >> 5) * 32;
    C = 1024; dOff = 0; dPitch = 4096;
  } else {
    const int i = (bid - 11264) * 256 + ty * 32 + tx;
    if (i < 3072)
      bqkv[i] = i < 1024 ? bq[i] : (i < 2048 ? bk[i - 1024] : bv[i - 2048]);
    return;
  }
  #pragma unroll
  for (int i = 0; i < 32; i += 8)
    tile[ty + i][tx] = src[(size_t)(r0 + ty + i) * C + c0 + tx];
  __syncthreads();
  #pragma unroll
  for (int i = 0; i < 32; i += 8)
    dst[(size_t)(c0 + ty + i + dOff) * dPitch + r0 + tx] =
        __float2bfloat16(tile[tx][ty + i]);
}

// ---- LayerNorm (+residual add; optionally init out = x2 + b2) ----
__global__ __launch_bounds__(256) void k_ln(const float* __restrict__ x,
                                            const float* __restrict__ y,
                                            const float* __restrict__ g,
                                            const float* __restrict__ bb,
                                            __hip_bfloat16* __restrict__ o,
                                            const float* __restrict__ badd,
                                            float* __restrict__ oinit) {
  __shared__ float sb[4];
  const int t = threadIdx.x;
  const size_t base = (size_t)blockIdx.x * 1024 + t * 4;
  const int c = t * 4;
  float4 xv = *(const float4*)(x + base);
  if (y) {
    float4 yv = *(const float4*)(y + base);
    xv.x += yv.x; xv.y += yv.y; xv.z += yv.z; xv.w += yv.w;
    float4 ov;
    ov.x = xv.x + badd[c + 0]; ov.y = xv.y + badd[c + 1];
    ov.z = xv.z + badd[c + 2]; ov.w = xv.w + badd[c + 3];
    *(float4*)(oinit + base) = ov;
  }
  const float mu = block_sum(xv.x + xv.y + xv.z + xv.w, sb) * (1.f / 1024.f);
  const float dx = xv.x - mu, dy = xv.y - mu, dz = xv.z - mu, dw = xv.w - mu;
  const float var = block_sum(dx * dx + dy * dy + dz * dz + dw * dw, sb) * (1.f / 1024.f);
  const float rs = rsqrtf(var + 1e-5f);
  o[base + 0] = __float2bfloat16(dx * rs * g[c + 0] + bb[c + 0]);
  o[base + 1] = __float2bfloat16(dy * rs * g[c + 1] + bb[c + 1]);
  o[base + 2] = __float2bfloat16(dz * rs * g[c + 2] + bb[c + 2]);
  o[base + 3] = __float2bfloat16(dw * rs * g[c + 3] + bb[c + 3]);
}

// ---- QKV GEMM: h1[4096,1024] @ Wqkv_t[3072,1024]^T, 4-phase ----
// 128x128 tile, grid(32,24)=768 blocks (XCD-swizzled), 512 thr, BK=64,
// 2 K-tiles/iter (8 iters), LDS 64KB -> 2 blocks/CU.
__global__ __launch_bounds__(512, 2) void k_gemm_qkv(
    const __hip_bfloat16* __restrict__ h1, const __hip_bfloat16* __restrict__ Wt,
    const float* __restrict__ bqkv, __hip_bfloat16* __restrict__ Q,
    __hip_bfloat16* __restrict__ K, __hip_bfloat16* __restrict__ Vt) {
  __shared__ alignas(16) short smem[32768];  // 64KB: Ae Ao Be Bo x 8192
  short* Ae = smem;
  short* Ao = smem + 8192;
  short* Be = smem + 16384;
  short* Bo = smem + 24576;
  int bx, by; xcd_swz(bx, by);
  const int row0 = bx * 128, col0 = by * 128;
  const int tid = threadIdx.x, lane = tid & 63, wid = tid >> 6;
  const int lr = lane & 15, lq = lane >> 4;
  const int wr = wid >> 2, wc = wid & 3;     // 2M x 4N: 64 rows x 32 cols
  const __hip_bfloat16* A = h1 + (size_t)row0 * 1024;
  const __hip_bfloat16* Bt = Wt + (size_t)col0 * 1024;

  auto STGA = [&](int k0, int h, short* dst) {
    const int rp = tid >> 3, P = tid & 7;    // rp 0-63
    const int r = ((rp >> 5) << 6) | (h << 5) | (rp & 31);
    const int g = P ^ (r & 7);
    stage16(A + (size_t)r * 1024 + k0 + g * 8, dst + r * 64 + P * 8);
  };
  auto STGB = [&](int k0, short* dst) {
    #pragma unroll
    for (int ii = 0; ii < 2; ii++) {
      const int f = tid + ii * 512;
      const int r = f >> 3, P = f & 7;
      const int g = P ^ (r & 7);
      stage16(Bt + (size_t)r * 1024 + k0 + g * 8, dst + r * 64 + P * 8);
    }
  };

  f32x4 acc[4][2] = {};
  bf16x8 af[2][2], bf[2][2];

  auto RDA = [&](const short* pa, int MH) {
    #pragma unroll
    for (int mi2 = 0; mi2 < 2; mi2++)
      #pragma unroll
      for (int ks = 0; ks < 2; ks++) {
        const int r = wr * 64 + MH * 32 + mi2 * 16 + lr;   // bit5 == MH
        af[mi2][ks] = *(const bf16x8*)(pa + r * 64 + (((ks * 4 + lq) ^ (r & 7)) << 3));
      }
  };
  auto RDB = [&](const short* pb) {
    #pragma unroll
    for (int ni = 0; ni < 2; ni++)
      #pragma unroll
      for (int ks = 0; ks < 2; ks++) {
        const int n = wc * 32 + ni * 16 + lr;
        bf[ni][ks] = *(const bf16x8*)(pb + n * 64 + (((ks * 4 + lq) ^ (n & 7)) << 3));
      }
  };

  STGB(0, Be); STGA(0, 0, Ae);
  STGA(0, 1, Ae);
  STGB(64, Bo); STGA(64, 0, Ao);
  asm volatile("s_waitcnt vmcnt(4)" ::: "memory");
  __syncthreads();

  for (int i = 0; i < 8; ++i) {
    const int kE1 = (i + 1) * 128, kO0 = i * 128 + 64, kO1 = kE1 + 64;
    const bool more = (i + 1 < 8);
    RDA(Ae, 0); RDB(Be);
    STGA(kO0, 1, Ao);
    asm volatile("s_waitcnt vmcnt(4)" ::: "memory");
    ph_sync();
    mmh<0>(acc, af, bf);
    RDA(Ae, 1);
    if (more) {
      STGB(kE1, Be); STGA(kE1, 0, Ae);
      asm volatile("s_waitcnt vmcnt(4)" ::: "memory");
    } else {
      asm volatile("s_waitcnt vmcnt(1)" ::: "memory");
    }
    ph_sync();
    mmh<1>(acc, af, bf);
    RDA(Ao, 0); RDB(Bo);
    if (more) {
      STGA(kE1, 1, Ae);
      asm volatile("s_waitcnt vmcnt(4)" ::: "memory");
    } else {
      asm volatile("s_waitcnt vmcnt(0)" ::: "memory");
    }
    ph_sync();
    mmh<0>(acc, af, bf);
    RDA(Ao, 1);
    if (more) {
      STGB(kO1, Bo); STGA(kO1, 0, Ao);
      asm volatile("s_waitcnt vmcnt(4)" ::: "memory");
    }
    ph_sync();
    mmh<1>(acc, af, bf);
  }

  // ---- Q/K/V scatter epilogue ----
  const int which = col0 >> 10;                 // uniform: 0=Q 1=K 2=V
  const int h0 = (col0 & 1023) >> 6;
  const int b = row0 >> 10, t0 = row0 & 1023;
  short* lc = smem;                             // 128*132 = 16896 shorts
  if (which < 2) {
    const float qs = (which == 0) ? LOG2E_SCALE : 1.f;
    #pragma unroll
    for (int mi = 0; mi < 4; mi++)
      #pragma unroll
      for (int ni = 0; ni < 2; ni++)
        #pragma unroll
        for (int rr = 0; rr < 4; rr++) {
          const int row = wr * 64 + (mi >> 1) * 32 + (mi & 1) * 16 + lq * 4 + rr;
          const int col = wc * 32 + ni * 16 + lr;
          lc[row * 132 + col] = f2bf_s((acc[mi][ni][rr] + bqkv[col0 + col]) * qs);
        }
    __syncthreads();
    __hip_bfloat16* O = which == 0 ? Q : K;
    #pragma unroll
    for (int c = 0; c < 4; c++) {
      const int f = tid + 512 * c;              // 2048 16B-chunks (128x128)
      const int r = f >> 4, cc = f & 15;
      const int col = cc * 8;
      const int head = h0 + (col >> 6), d = col & 63;
      float4 vv = *(const float4*)(lc + r * 132 + col);
      *(float4*)(O + (((size_t)(b * 16 + head)) << 16) + (t0 + r) * 64 + d) = vv;
    }
  } else {
    // transposed epilogue: lc[col][row]
    #pragma unroll
    for (int mi = 0; mi < 4; mi++)
      #pragma unroll
      for (int ni = 0; ni < 2; ni++)
        #pragma unroll
        for (int rr = 0; rr < 4; rr++) {
          const int row = wr * 64 + (mi >> 1) * 32 + (mi & 1) * 16 + lq * 4 + rr;
          const int col = wc * 32 + ni * 16 + lr;
          lc[col * 132 + row] = f2bf_s(acc[mi][ni][rr] + bqkv[col0 + col]);
        }
    __syncthreads();
    #pragma unroll
    for (int c = 0; c < 4; c++) {
      const int f = tid + 512 * c;
      const int dl = f >> 4, tc = f & 15;       // local d 0..127, t-chunk
      const int head = h0 + (dl >> 6), d = dl & 63;
      float4 vv = *(const float4*)(lc + dl * 132 + tc * 8);
      *(float4*)(Vt + (((size_t)(b * 16 + head)) << 16) + (size_t)d * 1024 +
                 t0 + tc * 8) = vv;
    }
  }
}

// ---- tail V sums: TV[hb][qt][d] = sum_{t >= (qt+1)*128} Vt[hb][d][t] ----
__global__ __launch_bounds__(256) void k_tailv(const __hip_bfloat16* __restrict__ Vt,
                                               float* __restrict__ TV) {
  __shared__ float ts[8][64];
  const int hb = blockIdx.x, tid = threadIdx.x;
  const __hip_bfloat16* Vh = Vt + ((size_t)hb << 16);
  for (int w = tid; w < 512; w += 256) {
    const int kt = w >> 6, d = w & 63;
    const short* p = (const short*)(Vh + (size_t)d * 1024 + kt * 128);
    float s = 0.f;
    for (int j = 0; j < 128; j += 8) {
      bf16x8 v = *(const bf16x8*)(p + j);
      #pragma unroll
      for (int e = 0; e < 8; e++) s += bf2f(v[e]);
    }
    ts[kt][d] = s;
  }
  __syncthreads();
  for (int w = tid; w < 512; w += 256) {
    const int qt = w >> 6, d = w & 63;
    float s = 0.f;
    for (int kt = qt + 1; kt < 8; kt++) s += ts[kt][d];
    TV[((size_t)hb * 8 + qt) * 64 + d] = s;
  }
}

// ---- fused attention: one block = (64 q-rows, one head); 1024 blocks ----
// Separate lK/lV buffers; 2 barriers per kt; K(kt+1) prefetched alongside
// V(kt) so its latency hides under softmax+PV; setprio on MFMA clusters.
__global__ __launch_bounds__(256, 3) void k_attn(
    const __hip_bfloat16* __restrict__ Q, const __hip_bfloat16* __restrict__ K,
    const __hip_bfloat16* __restrict__ Vt, const float* __restrict__ TV,
    float* __restrict__ y) {
  __shared__ short lp[64 * 130];   // P-tile (padded)
  __shared__ short lK[128 * 64];   // K-tile, swizzled
  __shared__ short lV[128 * 64];   // V^T-tile, swizzled
  const int hb = blockIdx.y;
  const int j = (blockIdx.y & 32) ? (15 - (int)blockIdx.x) : (int)blockIdx.x;
  const int q0 = j * 64;
  const int nkt = (j >> 1) + 1;    // K-tiles (128 wide) to compute
  const int tid = threadIdx.x, lane = tid & 63, wave = tid >> 6;
  const int lr = lane & 15, lq = lane >> 4;
  const int wm = wave * 16;        // wave owns q-rows [q0+wm, q0+wm+16)
  const __hip_bfloat16* Qh = Q + ((size_t)hb << 16);
  const __hip_bfloat16* Kh = K + ((size_t)hb << 16);
  const __hip_bfloat16* Vh = Vt + ((size_t)hb << 16);

  // Q A-frags: direct global loads (rows q0+wm+lr, cols s*32+lq*8)
  bf16x8 qf[2];
  #pragma unroll
  for (int s = 0; s < 2; s++)
    qf[s] = *(const bf16x8*)((const short*)Qh +
                             (size_t)(q0 + wm + lr) * 64 + s * 32 + lq * 8);

  f32x4 oacc[4] = {};
  float mrow[4], lrow[4];
  #pragma unroll
  for (int r = 0; r < 4; r++) { mrow[r] = -1e30f; lrow[r] = 0.f; }

  // prologue: stage K(0)
  for (int c = tid; c < 1024; c += 256)
    stage16(Kh + (size_t)(c >> 3) * 64 + (((c & 7) ^ ((c >> 3) & 7)) << 3),
            lK + c * 8);
  __syncthreads();  // K(0) visible

  for (int kt = 0; kt < nkt; kt++) {
    const int k0 = kt * 128;
    // ---- QK^T from lK ----
    f32x4 sacc[8] = {};
    __builtin_amdgcn_s_setprio(1);
    #pragma unroll
    for (int s = 0; s < 2; s++) {
      bf16x8 bf[8];
      #pragma unroll
      for (int ni = 0; ni < 8; ni++) {
        const int n = ni * 16 + lr;
        bf[ni] = *(const bf16x8*)(lK + n * 64 + (((s * 4 + lq) ^ (n & 7)) << 3));
      }
      #pragma unroll
      for (int ni = 0; ni < 8; ni++)
        sacc[ni] = __builtin_amdgcn_mfma_f32_16x16x32_bf16(
            qf[s], bf[ni], sacc[ni], 0, 0, 0);
    }
    __builtin_amdgcn_s_setprio(0);
    __syncthreads();  // barA: lK frag reads + prev PV's lp/lV reads done
    // ---- V(kt) + K(kt+1) DMA (latency hides under softmax below) ----
    for (int c = tid; c < 1024; c += 256)
      stage16(Vh + (size_t)(c >> 4) * 1024 + k0 + (((c & 15) ^ ((c >> 4) & 15)) << 3),
              lV + c * 8);
    if (kt + 1 < nkt) {
      const int k1 = k0 + 128;
      for (int c = tid; c < 1024; c += 256)
        stage16(Kh + (size_t)(k1 + (c >> 3)) * 64 + (((c & 7) ^ ((c >> 3) & 7)) << 3),
                lK + c * 8);
    }
    // ---- online softmax, base-2 domain ----
    const bool last = (kt == nkt - 1);
    #pragma unroll
    for (int r = 0; r < 4; r++) {
      const int grow = q0 + wm + lq * 4 + r;   // global q row
      float tmax = -1e30f;
      #pragma unroll
      for (int ni = 0; ni < 8; ni++) {
        float v = sacc[ni][r];
        if (last && (k0 + ni * 16 + lr) > grow) v = MASK2;
        sacc[ni][r] = v;
        tmax = fmaxf(tmax, v);
      }
      #pragma unroll
      for (int msk = 8; msk; msk >>= 1) tmax = fmaxf(tmax, __shfl_xor(tmax, msk));
      const float mn = fmaxf(mrow[r], tmax);
      const float al = __builtin_amdgcn_exp2f(mrow[r] - mn);
      float rs = 0.f;
      #pragma unroll
      for (int ni = 0; ni < 8; ni++) {
        const float pv = __builtin_amdgcn_exp2f(sacc[ni][r] - mn);
        sacc[ni][r] = pv;
        rs += pv;
      }
      #pragma unroll
      for (int msk = 8; msk; msk >>= 1) rs += __shfl_xor(rs, msk);
      mrow[r] = mn;
      lrow[r] = lrow[r] * al + rs;
      #pragma unroll
      for (int ni = 0; ni < 4; ni++) oacc[ni][r] *= al;
    }
    // P -> lp (padded pitch 130)
    #pragma unroll
    for (int r = 0; r < 4; r++) {
      const int row = wm + lq * 4 + r;
      #pragma unroll
      for (int ni = 0; ni < 8; ni++)
        lp[row * 130 + ni * 16 + lr] = f2bf_s(sacc[ni][r]);
    }
    __syncthreads();  // barB: V(kt)+K(kt+1) landed (vmcnt drain) + P visible
    // ---- PV from lp, lV ----
    __builtin_amdgcn_s_setprio(1);
    #pragma unroll
    for (int ks = 0; ks < 4; ks++) {
      bf16x8 pa, vb[4];
      pa = *(const bf16x8*)(lp + (wm + lr) * 130 + ks * 32 + lq * 8);
      #pragma unroll
      for (int ni = 0; ni < 4; ni++) {
        const int d = ni * 16 + lr;
        vb[ni] = *(const bf16x8*)(lV + d * 128 + (((ks * 4 + lq) ^ (d & 15)) << 3));
      }
      #pragma unroll
      for (int ni = 0; ni < 4; ni++)
        oacc[ni] = __builtin_amdgcn_mfma_f32_16x16x32_bf16(
            pa, vb[ni], oacc[ni], 0, 0, 0);
    }
    __builtin_amdgcn_s_setprio(0);
    // no barrier here: next QK reads lK (disjoint from lp/lV); barA covers reuse
  }

  const int b = hb >> 4, h = hb & 15;
  const float cv = (float)(1024 - nkt * 128);
  const float* tv = TV + ((size_t)hb * 8 + (j >> 1)) * 64;
  #pragma unroll
  for (int r = 0; r < 4; r++) {
    const int t = q0 + wm + lq * 4 + r;
    const float tail = __builtin_amdgcn_exp2f(MASK2 - mrow[r]);
    const float inv = 1.f / (lrow[r] + cv * tail);
    #pragma unroll
    for (int ni = 0; ni < 4; ni++) {
      const int d = ni * 16 + lr;
      y[((size_t)(b * 1024 + t) << 10) + h * 64 + d] =
          (oacc[ni][r] + tail * tv[d]) * inv;
    }
  }
}

// ---- MLP1: h2[4096,1024] @ W1t[4096,1024]^T + b1 -> tanh-GELU -> G bf16 ----
// 256x256 tile (XCD-swizzled grid 16x16), 512 thr, BK=64, 8-phase.
// R23: epilogue 2 passes of 128 rows (lc 128x264 = 67.6KB).
__global__ __launch_bounds__(512, 2) void k_gemm_mlp1(const __hip_bfloat16* __restrict__ h2,
                                                      const __hip_bfloat16* __restrict__ W1t,
                                                      const float* __restrict__ b1,
                                                      __hip_bfloat16* __restrict__ G) {
  __shared__ alignas(16) short smem[65536];  // 128KB: Ae Ao Be Bo x 16384
  short* Ae = smem;
  short* Ao = smem + 16384;
  short* Be = smem + 32768;
  short* Bo = smem + 49152;
  int bx, by; xcd_swz(bx, by);
  const int row0 = bx * 256, col0 = by * 256;
  const int tid = threadIdx.x, lane = tid & 63, wid = tid >> 6;
  const int lr = lane & 15, lq = lane >> 4;
  const int wr = wid >> 2, wc = wid & 3;
  const __hip_bfloat16* A = h2 + (size_t)row0 * 1024;
  const __hip_bfloat16* Bt = W1t + (size_t)col0 * 1024;

  auto STG = [&](const __hip_bfloat16* src, int k0, int h, short* dst, int SH) {
    #pragma unroll
    for (int ii = 0; ii < 2; ii++) {
      const int f = tid + ii * 512;
      const int rp = f >> 3, P = f & 7;
      const int r = ((rp >> SH) << (SH + 1)) | (h << SH) | (rp & ((1 << SH) - 1));
      const int g = P ^ (r & 7);
      stage16(src + (size_t)r * 1024 + k0 + g * 8, dst + r * 64 + P * 8);
    }
  };

  f32x4 acc[8][4] = {};
  bf16x8 af[4][2], bf[2][2];

  // prologue: E0 (4 parts) + O0.A0, O0.B0; vmcnt(4) retires E0 (FIFO).
  STG(A, 0, 0, Ae, 6);  STG(Bt, 0, 0, Be, 5);
  STG(A, 0, 1, Ae, 6);  STG(Bt, 0, 1, Be, 5);
  STG(A, 64, 0, Ao, 6); STG(Bt, 64, 0, Bo, 5);
  asm volatile("s_waitcnt vmcnt(4)" ::: "memory");
  __syncthreads();

  for (int i = 0; i < 8; ++i) {
    const int kE1 = (i + 1) * 128;       // next even K-tile
    const int kO0 = i * 128 + 64;        // this iter's odd K-tile
    const int kO1 = kE1 + 64;            // next odd K-tile
    const bool more = (i + 1 < 8);
    ph_read<0, 0>(Ae, Be, wr, wc, lr, lq, af, bf);
    STG(A, kO0, 1, Ao, 6);
    ph_sync();
    ph_mfma<0, 0>(acc, af, bf);
    ph_read<0, 1>(Ae, Be, wr, wc, lr, lq, af, bf);
    STG(Bt, kO0, 1, Bo, 5);
    ph_sync();
    ph_mfma<0, 1>(acc, af, bf);
    ph_read<1, 0>(Ae, Be, wr, wc, lr, lq, af, bf);
    if (more) STG(A, kE1, 0, Ae, 6);
    ph_sync();
    ph_mfma<1, 0>(acc, af, bf);
    ph_read<1, 1>(Ae, Be, wr, wc, lr, lq, af, bf);
    if (more) {
      STG(Bt, kE1, 0, Be, 5);
      asm volatile("s_waitcnt vmcnt(4)" ::: "memory");
    } else {
      asm volatile("s_waitcnt vmcnt(0)" ::: "memory");
    }
    ph_sync();
    ph_mfma<1, 1>(acc, af, bf);
    ph_read<0, 0>(Ao, Bo, wr, wc, lr, lq, af, bf);
    if (more) STG(A, kE1, 1, Ae, 6);
    ph_sync();
    ph_mfma<0, 0>(acc, af, bf);
    ph_read<0, 1>(Ao, Bo, wr, wc, lr, lq, af, bf);
    if (more) STG(Bt, kE1, 1, Be, 5);
    ph_sync();
    ph_mfma<0, 1>(acc, af, bf);
    ph_read<1, 0>(Ao, Bo, wr, wc, lr, lq, af, bf);
    if (more) STG(A, kO1, 0, Ao, 6);
    ph_sync();
    ph_mfma<1, 0>(acc, af, bf);
    ph_read<1, 1>(Ao, Bo, wr, wc, lr, lq, af, bf);
    if (more) {
      STG(Bt, kO1, 0, Bo, 5);
      asm volatile("s_waitcnt vmcnt(4)" ::: "memory");
    }
    ph_sync();
    ph_mfma<1, 1>(acc, af, bf);
  }

  // epilogue: tanh-GELU -> bf16 via 2x 128-row lc passes (lc = smem)
  short* lc = smem;                      // 128*264 = 33792 shorts (67.6KB)
  #pragma unroll
  for (int pr = 0; pr < 2; pr++) {
    if (wr == pr) {
      #pragma unroll
      for (int mi = 0; mi < 8; mi++)
        #pragma unroll
        for (int ni = 0; ni < 4; ni++)
          #pragma unroll
          for (int rr = 0; rr < 4; rr++) {
            const int rloc = mi * 16 + lq * 4 + rr;
            const int col = wc * 64 + ni * 16 + lr;
            float v = acc[mi][ni][rr] + b1[col0 + col];
            const float u2 = fminf(v * (2.3022079f + 0.1029434f * v * v), 80.f);
            const float e = __builtin_amdgcn_exp2f(u2);
            v = v * e * __builtin_amdgcn_rcpf(e + 1.f);
            lc[rloc * 264 + col] = f2bf_s(v);
          }
    }
    __syncthreads();
    #pragma unroll
    for (int c = 0; c < 8; c++) {
      const int f = tid + 512 * c;       // 4096 chunks: 128 rows x 32 chunks
      const int r = f >> 5, cc = f & 31;
      float4 vv = *(const float4*)(lc + r * 264 + cc * 8);
      *(float4*)(G + ((size_t)(row0 + pr * 128 + r) << 12) + col0 + cc * 8) = vv;
    }
    __syncthreads();
  }
}

// ---- MLP2: out += G @ W2t^T, NO split-K, NO atomics (RMW epilogue) ----
// 128x128 tile, grid(32,8)=256 blocks (XCD-swizzled), K=4096, 512 thr,
// BK=64, 2 K-tiles/iter (32 iters), 4 phases x 8 MFMA, LDS 64KB.
__global__ __launch_bounds__(512, 2) void k_gemm_mlp2(const __hip_bfloat16* __restrict__ G,
                                                      const __hip_bfloat16* __restrict__ W2t,
                                                      float* __restrict__ out) {
  __shared__ alignas(16) short smem[32768];  // 64KB: Ae Ao Be Bo x 8192
  short* Ae = smem;
  short* Ao = smem + 8192;
  short* Be = smem + 16384;
  short* Bo = smem + 24576;
  int bx, by; xcd_swz(bx, by);
  const int row0 = bx * 128, col0 = by * 128;
  const int tid = threadIdx.x, lane = tid & 63, wid = tid >> 6;
  const int lr = lane & 15, lq = lane >> 4;
  const int wr = wid >> 2, wc = wid & 3;     // 2M x 4N: 64 rows x 32 cols
  const __hip_bfloat16* A = G + (size_t)row0 * 4096;
  const __hip_bfloat16* Bt = W2t + (size_t)col0 * 4096;

  auto STGA = [&](int k0, int h, short* dst) {
    const int rp = tid >> 3, P = tid & 7;    // rp 0-63
    const int r = ((rp >> 5) << 6) | (h << 5) | (rp & 31);
    const int g = P ^ (r & 7);
    stage16(A + (size_t)r * 4096 + k0 + g * 8, dst + r * 64 + P * 8);
  };
  auto STGB = [&](int k0, short* dst) {
    #pragma unroll
    for (int ii = 0; ii < 2; ii++) {
      const int f = tid + ii * 512;
      const int r = f >> 3, P = f & 7;
      const int g = P ^ (r & 7);
      stage16(Bt + (size_t)r * 4096 + k0 + g * 8, dst + r * 64 + P * 8);
    }
  };

  f32x4 acc[4][2] = {};
  bf16x8 af[2][2], bf[2][2];

  auto RDA = [&](const short* pa, int MH) {
    #pragma unroll
    for (int mi2 = 0; mi2 < 2; mi2++)
      #pragma unroll
      for (int ks = 0; ks < 2; ks++) {
        const int r = wr * 64 + MH * 32 + mi2 * 16 + lr;   // bit5 == MH
        af[mi2][ks] = *(const bf16x8*)(pa + r * 64 + (((ks * 4 + lq) ^ (r & 7)) << 3));
      }
  };
  auto RDB = [&](const short* pb) {
    #pragma unroll
    for (int ni = 0; ni < 2; ni++)
      #pragma unroll
      for (int ks = 0; ks < 2; ks++) {
        const int n = wc * 32 + ni * 16 + lr;
        bf[ni][ks] = *(const bf16x8*)(pb + n * 64 + (((ks * 4 + lq) ^ (n & 7)) << 3));
      }
  };

  STGB(0, Be); STGA(0, 0, Ae);
  STGA(0, 1, Ae);
  STGB(64, Bo); STGA(64, 0, Ao);
  asm volatile("s_waitcnt vmcnt(4)" ::: "memory");
  __syncthreads();

  for (int i = 0; i < 32; ++i) {
    const int kE1 = (i + 1) * 128, kO0 = i * 128 + 64, kO1 = kE1 + 64;
    const bool more = (i + 1 < 32);
    RDA(Ae, 0); RDB(Be);
    STGA(kO0, 1, Ao);
    asm volatile("s_waitcnt vmcnt(4)" ::: "memory");
    ph_sync();
    mmh<0>(acc, af, bf);
    RDA(Ae, 1);
    if (more) {
      STGB(kE1, Be); STGA(kE1, 0, Ae);
      asm volatile("s_waitcnt vmcnt(4)" ::: "memory");
    } else {
      asm volatile("s_waitcnt vmcnt(1)" ::: "memory");
    }
    ph_sync();
    mmh<1>(acc, af, bf);
    RDA(Ao, 0); RDB(Bo);
    if (more) {
      STGA(kE1, 1, Ae);
      asm volatile("s_waitcnt vmcnt(4)" ::: "memory");
    } else {
      asm volatile("s_waitcnt vmcnt(0)" ::: "memory");
    }
    ph_sync();
    mmh<0>(acc, af, bf);
    RDA(Ao, 1);
    if (more) {
      STGB(kO1, Bo); STGA(kO1, 0, Ao);
      asm volatile("s_waitcnt vmcnt(4)" ::: "memory");
    }
    ph_sync();
    mmh<1>(acc, af, bf);
  }

  // epilogue: plain RMW (out pre-initialized with x2 + b2 by k_ln)
  #pragma unroll
  for (int mi = 0; mi < 4; mi++)
    #pragma unroll
    for (int ni = 0; ni < 2; ni++)
      #pragma unroll
      for (int rr = 0; rr < 4; rr++) {
        const int grow = row0 + wr * 64 + (mi >> 1) * 32 + (mi & 1) * 16 + lq * 4 + rr;
        const int gcol = col0 + wc * 32 + ni * 16 + lr;
        float* p = out + (((size_t)grow << 10) + gcol);
        *p += acc[mi][ni][rr];
      }
}

extern "C" void kernel_launch(void* const* d_in, const int* in_sizes, int n_in,
                              void* d_out, int out_size, void* d_ws, size_t ws_size,
                              hipStream_t stream) {
  const float* x     = (const float*)d_in[0];
  const float* ln1_g = (const float*)d_in[1];
  const float* ln1_b = (const float*)d_in[2];
  const float* ln2_g = (const float*)d_in[3];
  const float* ln2_b = (const float*)d_in[4];
  const float* Wq    = (const float*)d_in[5];
  const float* bq    = (const float*)d_in[6];
  const float* Wk    = (const float*)d_in[7];
  const float* bk    = (const float*)d_in[8];
  const float* Wv    = (const float*)d_in[9];
  const float* bv    = (const float*)d_in[10];
  const float* W1    = (const float*)d_in[11];
  const float* b1    = (const float*)d_in[12];
  const float* W2    = (const float*)d_in[13];
  const float* b2    = (const float*)d_in[14];
  float* out = (float*)d_out;

  char* p = (char*)d_ws;
  auto alloc = [&](size_t bytes) { char* r = p; p += (bytes + 255) & ~(size_t)255; return r; };
  __hip_bfloat16* wqkv = (__hip_bfloat16*)alloc(3072 * 1024 * 2);
  __hip_bfloat16* w1t  = (__hip_bfloat16*)alloc(4096 * 1024 * 2);
  __hip_bfloat16* w2t  = (__hip_bfloat16*)alloc(1024 * 4096 * 2);
  float*          bqkv = (float*)alloc(3072 * 4);
  __hip_bfloat16* h1   = (__hip_bfloat16*)alloc(4096 * 1024 * 2);
  __hip_bfloat16* Qb   = (__hip_bfloat16*)alloc((size_t)64 * 65536 * 2);  // [64][1024][64]
  __hip_bfloat16* Kb   = (__hip_bfloat16*)alloc((size_t)64 * 65536 * 2);
  __hip_bfloat16* Vt   = (__hip_bfloat16*)alloc((size_t)64 * 65536 * 2);  // [64][64][1024]
  float*          TV   = (float*)alloc((size_t)64 * 8 * 64 * 4);
  float*          yb   = (float*)alloc((size_t)4096 * 1024 * 4);
  __hip_bfloat16* h2   = (__hip_bfloat16*)alloc(4096 * 1024 * 2);
  __hip_bfloat16* G    = (__hip_bfloat16*)alloc((size_t)4096 * 4096 * 2);
  (void)ws_size; (void)in_sizes; (void)n_in; (void)out_size;

  const dim3 b256(256), bt(32, 8);
  k_prep<<<11276, bt, 0, stream>>>(Wq, Wk, Wv, wqkv, W1, w1t, W2, w2t,
                                   bq, bk, bv, bqkv);

  k_ln<<<4096, b256, 0, stream>>>(x, nullptr, ln1_g, ln1_b, h1, nullptr, nullptr);
  k_gemm_qkv<<<dim3(32, 24), dim3(512), 0, stream>>>(h1, wqkv, bqkv, Qb, Kb, Vt);
  k_tailv<<<64, b256, 0, stream>>>(Vt, TV);
  k_attn<<<dim3(16, 64), b256, 0, stream>>>(Qb, Kb, Vt, TV, yb);

  k_ln<<<4096, b256, 0, stream>>>(x, yb, ln2_g, ln2_b, h2, b2, out);
  k_gemm_mlp1<<<dim3(16, 16), dim3(512), 0, stream>>>(h2, w1t, b1, G);
  k_gemm_mlp2<<<dim3(32, 8), dim3(512), 0, stream>>>(G, w2t, out);
}

// Round 14
// 303.223 us; speedup vs baseline: 1.0093x; 1.0093x over previous
//
#include <hip/hip_runtime.h>
#include <hip/hip_bf16.h>
#include <math.h>

// Transformer block (pre-LN attn + MLP), B=4 T=1024 H=1024 K=16 HD=64.
// R24 == R23 minus the XCD swizzle (clean A/B). R23's profile showed the
// swizzle uniformly stalled mlp1 (84us, HBM 1417->849 GB/s, MfmaUtil
// 26->15, FETCH unchanged): the round-robin flat->XCD assumption is wrong
// on this part, so the remap scattered each XCD across ALL panels.
// Kept from R23: (1) mlp1 2-pass epilogue (128-row lc, 67.6KB); (2) fused
// k_prep (tcvt3 + 2x tcvt + pack_bias in one 11276-block launch).
// GEMM structure (session-validated R19-R22): counted-vmcnt phase loops;
// mlp1 256x256 8-phase; mlp2 128x128 4-phase no-split-K RMW; qkv 128x128
// 4-phase with Q/K/V scatter epilogue.
// Attention: fused flash-style, 64-row Q-tiles, separate lK/lV, 2 barriers
// per kt, K(kt+1) prefetch hidden under softmax, setprio on MFMA clusters;
// masked logits FILLED with 1e-9; fully-masked K-tiles contribute
// exp(1e-9-m)*suffixV analytically (TV precomputed).

typedef __attribute__((ext_vector_type(8))) short bf16x8;
typedef __attribute__((ext_vector_type(4))) float f32x4;

#define DEVINL __device__ __forceinline__

#define LOG2E_SCALE 0.18033688f      /* 0.125 * log2(e) */
#define MASK2 1.4426950408889634e-9f /* 1e-9 * log2(e) */

DEVINL void stage16(const __hip_bfloat16* g, short* l) {
  __builtin_amdgcn_global_load_lds(
      (const __attribute__((address_space(1))) unsigned int*)g,
      (__attribute__((address_space(3))) unsigned int*)l, 16, 0, 0);
}

DEVINL float bf2f(short u) {
  unsigned x = ((unsigned)(unsigned short)u) << 16;
  float f; __builtin_memcpy(&f, &x, 4); return f;
}

DEVINL short f2bf_s(float f) {
  __hip_bfloat16 h = __float2bfloat16(f);
  short s; __builtin_memcpy(&s, &h, 2); return s;
}

DEVINL float block_sum(float v, float* sb) {
  #pragma unroll
  for (int o = 32; o; o >>= 1) v += __shfl_down(v, o);
  const int lane = threadIdx.x & 63, w = threadIdx.x >> 6;
  if (lane == 0) sb[w] = v;
  __syncthreads();
  float r = sb[0] + sb[1] + sb[2] + sb[3];
  __syncthreads();
  return r;
}

// ======== shared phase-schedule helpers ========
DEVINL void ph_sync() {
  __builtin_amdgcn_s_barrier();
  asm volatile("s_waitcnt lgkmcnt(0)" ::: "memory");
  __builtin_amdgcn_sched_barrier(0);
}

// 8-MFMA phase (acc[4][2]; af = A-half MH, bf = 2 N-frags) — mlp2/qkv shape
template<int MH>
DEVINL void mmh(f32x4 (&acc)[4][2], bf16x8 (&af)[2][2], bf16x8 (&bf)[2][2]) {
  __builtin_amdgcn_s_setprio(1);
  #pragma unroll
  for (int mi2 = 0; mi2 < 2; mi2++)
    #pragma unroll
    for (int ni = 0; ni < 2; ni++)
      #pragma unroll
      for (int ks = 0; ks < 2; ks++)
        acc[MH * 2 + mi2][ni] = __builtin_amdgcn_mfma_f32_16x16x32_bf16(
            af[mi2][ks], bf[ni][ks], acc[MH * 2 + mi2][ni], 0, 0, 0);
  __builtin_amdgcn_s_setprio(0);
  __builtin_amdgcn_s_barrier();
}

// 16-MFMA phase for mlp1 (acc[8][4])
template<int MH, int NH>
DEVINL void ph_read(const short* pa, const short* pb, int wr, int wc,
                    int lr, int lq, bf16x8 (&af)[4][2], bf16x8 (&bf)[2][2]) {
  if (NH == 0) {
    #pragma unroll
    for (int mi2 = 0; mi2 < 4; mi2++)
      #pragma unroll
      for (int ks = 0; ks < 2; ks++) {
        const int r = wr * 128 + MH * 64 + mi2 * 16 + lr;
        af[mi2][ks] = *(const bf16x8*)(pa + r * 64 + (((ks * 4 + lq) ^ (r & 7)) << 3));
      }
  }
  #pragma unroll
  for (int ni2 = 0; ni2 < 2; ni2++)
    #pragma unroll
    for (int ks = 0; ks < 2; ks++) {
      const int n = wc * 64 + NH * 32 + ni2 * 16 + lr;
      bf[ni2][ks] = *(const bf16x8*)(pb + n * 64 + (((ks * 4 + lq) ^ (n & 7)) << 3));
    }
}

template<int MH, int NH>
DEVINL void ph_mfma(f32x4 (&acc)[8][4], bf16x8 (&af)[4][2], bf16x8 (&bf)[2][2]) {
  __builtin_amdgcn_s_setprio(1);
  #pragma unroll
  for (int mi2 = 0; mi2 < 4; mi2++)
    #pragma unroll
    for (int ni2 = 0; ni2 < 2; ni2++)
      #pragma unroll
      for (int ks = 0; ks < 2; ks++)
        acc[MH * 4 + mi2][NH * 2 + ni2] = __builtin_amdgcn_mfma_f32_16x16x32_bf16(
            af[mi2][ks], bf[ni2][ks], acc[MH * 4 + mi2][NH * 2 + ni2], 0, 0, 0);
  __builtin_amdgcn_s_setprio(0);
  __builtin_amdgcn_s_barrier();
}

// ---- fused prep: W transposes (f32->bf16) + bias pack, one launch ----
// blocks [0,3072): Wq/Wk/Wv -> wqkv; [3072,7168): W1 -> w1t;
// [7168,11264): W2 -> w2t; [11264,11276): pack bqkv.
__global__ __launch_bounds__(256) void k_prep(
    const float* __restrict__ Wq, const float* __restrict__ Wk,
    const float* __restrict__ Wv, __hip_bfloat16* __restrict__ wqkv,
    const float* __restrict__ W1, __hip_bfloat16* __restrict__ w1t,
    const float* __restrict__ W2, __hip_bfloat16* __restrict__ w2t,
    const float* __restrict__ bq, const float* __restrict__ bk,
    const float* __restrict__ bv, float* __restrict__ bqkv) {
  __shared__ float tile[32][33];
  const int bid = blockIdx.x;
  const int tx = threadIdx.x, ty = threadIdx.y;  // (32,8)
  const float* src; __hip_bfloat16* dst;
  int c0, r0, C, dOff, dPitch;
  if (bid < 3072) {
    const int z = bid >> 10, rem = bid & 1023;
    src = z == 0 ? Wq : (z == 1 ? Wk : Wv); dst = wqkv;
    c0 = (rem & 31) * 32; r0 = (rem >> 5) * 32;
    C = 1024; dOff = z << 10; dPitch = 1024;
  } else if (bid < 7168) {
    const int rem = bid - 3072;
    src = W1; dst = w1t;
    c0 = (rem & 127) * 32; r0 = (rem >> 7) * 32;
    C = 4096; dOff = 0; dPitch = 1024;
  } else if (bid < 11264) {
    const int rem = bid - 7168;
    src = W2; dst = w2t;
    c0 = (rem & 31) * 32; r0 = (rem >> 5) * 32;
    C = 1024; dOff = 0; dPitch = 4096;
  } else {
    const int i = (bid - 11264) * 256 + ty * 32 + tx;
    if (i < 3072)
      bqkv[i] = i < 1024 ? bq[i] : (i < 2048 ? bk[i - 1024] : bv[i - 2048]);
    return;
  }
  #pragma unroll
  for (int i = 0; i < 32; i += 8)
    tile[ty + i][tx] = src[(size_t)(r0 + ty + i) * C + c0 + tx];
  __syncthreads();
  #pragma unroll
  for (int i = 0; i < 32; i += 8)
    dst[(size_t)(c0 + ty + i + dOff) * dPitch + r0 + tx] =
        __float2bfloat16(tile[tx][ty + i]);
}

// ---- LayerNorm (+residual add; optionally init out = x2 + b2) ----
__global__ __launch_bounds__(256) void k_ln(const float* __restrict__ x,
                                            const float* __restrict__ y,
                                            const float* __restrict__ g,
                                            const float* __restrict__ bb,
                                            __hip_bfloat16* __restrict__ o,
                                            const float* __restrict__ badd,
                                            float* __restrict__ oinit) {
  __shared__ float sb[4];
  const int t = threadIdx.x;
  const size_t base = (size_t)blockIdx.x * 1024 + t * 4;
  const int c = t * 4;
  float4 xv = *(const float4*)(x + base);
  if (y) {
    float4 yv = *(const float4*)(y + base);
    xv.x += yv.x; xv.y += yv.y; xv.z += yv.z; xv.w += yv.w;
    float4 ov;
    ov.x = xv.x + badd[c + 0]; ov.y = xv.y + badd[c + 1];
    ov.z = xv.z + badd[c + 2]; ov.w = xv.w + badd[c + 3];
    *(float4*)(oinit + base) = ov;
  }
  const float mu = block_sum(xv.x + xv.y + xv.z + xv.w, sb) * (1.f / 1024.f);
  const float dx = xv.x - mu, dy = xv.y - mu, dz = xv.z - mu, dw = xv.w - mu;
  const float var = block_sum(dx * dx + dy * dy + dz * dz + dw * dw, sb) * (1.f / 1024.f);
  const float rs = rsqrtf(var + 1e-5f);
  o[base + 0] = __float2bfloat16(dx * rs * g[c + 0] + bb[c + 0]);
  o[base + 1] = __float2bfloat16(dy * rs * g[c + 1] + bb[c + 1]);
  o[base + 2] = __float2bfloat16(dz * rs * g[c + 2] + bb[c + 2]);
  o[base + 3] = __float2bfloat16(dw * rs * g[c + 3] + bb[c + 3]);
}

// ---- QKV GEMM: h1[4096,1024] @ Wqkv_t[3072,1024]^T, 4-phase ----
// 128x128 tile, grid(32,24)=768 blocks, 512 thr, BK=64,
// 2 K-tiles/iter (8 iters), LDS 64KB -> 2 blocks/CU.
__global__ __launch_bounds__(512, 2) void k_gemm_qkv(
    const __hip_bfloat16* __restrict__ h1, const __hip_bfloat16* __restrict__ Wt,
    const float* __restrict__ bqkv, __hip_bfloat16* __restrict__ Q,
    __hip_bfloat16* __restrict__ K, __hip_bfloat16* __restrict__ Vt) {
  __shared__ alignas(16) short smem[32768];  // 64KB: Ae Ao Be Bo x 8192
  short* Ae = smem;
  short* Ao = smem + 8192;
  short* Be = smem + 16384;
  short* Bo = smem + 24576;
  const int row0 = blockIdx.x * 128, col0 = blockIdx.y * 128;
  const int tid = threadIdx.x, lane = tid & 63, wid = tid >> 6;
  const int lr = lane & 15, lq = lane >> 4;
  const int wr = wid >> 2, wc = wid & 3;     // 2M x 4N: 64 rows x 32 cols
  const __hip_bfloat16* A = h1 + (size_t)row0 * 1024;
  const __hip_bfloat16* Bt = Wt + (size_t)col0 * 1024;

  auto STGA = [&](int k0, int h, short* dst) {
    const int rp = tid >> 3, P = tid & 7;    // rp 0-63
    const int r = ((rp >> 5) << 6) | (h << 5) | (rp & 31);
    const int g = P ^ (r & 7);
    stage16(A + (size_t)r * 1024 + k0 + g * 8, dst + r * 64 + P * 8);
  };
  auto STGB = [&](int k0, short* dst) {
    #pragma unroll
    for (int ii = 0; ii < 2; ii++) {
      const int f = tid + ii * 512;
      const int r = f >> 3, P = f & 7;
      const int g = P ^ (r & 7);
      stage16(Bt + (size_t)r * 1024 + k0 + g * 8, dst + r * 64 + P * 8);
    }
  };

  f32x4 acc[4][2] = {};
  bf16x8 af[2][2], bf[2][2];

  auto RDA = [&](const short* pa, int MH) {
    #pragma unroll
    for (int mi2 = 0; mi2 < 2; mi2++)
      #pragma unroll
      for (int ks = 0; ks < 2; ks++) {
        const int r = wr * 64 + MH * 32 + mi2 * 16 + lr;   // bit5 == MH
        af[mi2][ks] = *(const bf16x8*)(pa + r * 64 + (((ks * 4 + lq) ^ (r & 7)) << 3));
      }
  };
  auto RDB = [&](const short* pb) {
    #pragma unroll
    for (int ni = 0; ni < 2; ni++)
      #pragma unroll
      for (int ks = 0; ks < 2; ks++) {
        const int n = wc * 32 + ni * 16 + lr;
        bf[ni][ks] = *(const bf16x8*)(pb + n * 64 + (((ks * 4 + lq) ^ (n & 7)) << 3));
      }
  };

  STGB(0, Be); STGA(0, 0, Ae);
  STGA(0, 1, Ae);
  STGB(64, Bo); STGA(64, 0, Ao);
  asm volatile("s_waitcnt vmcnt(4)" ::: "memory");
  __syncthreads();

  for (int i = 0; i < 8; ++i) {
    const int kE1 = (i + 1) * 128, kO0 = i * 128 + 64, kO1 = kE1 + 64;
    const bool more = (i + 1 < 8);
    RDA(Ae, 0); RDB(Be);
    STGA(kO0, 1, Ao);
    asm volatile("s_waitcnt vmcnt(4)" ::: "memory");
    ph_sync();
    mmh<0>(acc, af, bf);
    RDA(Ae, 1);
    if (more) {
      STGB(kE1, Be); STGA(kE1, 0, Ae);
      asm volatile("s_waitcnt vmcnt(4)" ::: "memory");
    } else {
      asm volatile("s_waitcnt vmcnt(1)" ::: "memory");
    }
    ph_sync();
    mmh<1>(acc, af, bf);
    RDA(Ao, 0); RDB(Bo);
    if (more) {
      STGA(kE1, 1, Ae);
      asm volatile("s_waitcnt vmcnt(4)" ::: "memory");
    } else {
      asm volatile("s_waitcnt vmcnt(0)" ::: "memory");
    }
    ph_sync();
    mmh<0>(acc, af, bf);
    RDA(Ao, 1);
    if (more) {
      STGB(kO1, Bo); STGA(kO1, 0, Ao);
      asm volatile("s_waitcnt vmcnt(4)" ::: "memory");
    }
    ph_sync();
    mmh<1>(acc, af, bf);
  }

  // ---- Q/K/V scatter epilogue ----
  const int which = col0 >> 10;                 // uniform: 0=Q 1=K 2=V
  const int h0 = (col0 & 1023) >> 6;
  const int b = row0 >> 10, t0 = row0 & 1023;
  short* lc = smem;                             // 128*132 = 16896 shorts
  if (which < 2) {
    const float qs = (which == 0) ? LOG2E_SCALE : 1.f;
    #pragma unroll
    for (int mi = 0; mi < 4; mi++)
      #pragma unroll
      for (int ni = 0; ni < 2; ni++)
        #pragma unroll
        for (int rr = 0; rr < 4; rr++) {
          const int row = wr * 64 + (mi >> 1) * 32 + (mi & 1) * 16 + lq * 4 + rr;
          const int col = wc * 32 + ni * 16 + lr;
          lc[row * 132 + col] = f2bf_s((acc[mi][ni][rr] + bqkv[col0 + col]) * qs);
        }
    __syncthreads();
    __hip_bfloat16* O = which == 0 ? Q : K;
    #pragma unroll
    for (int c = 0; c < 4; c++) {
      const int f = tid + 512 * c;              // 2048 16B-chunks (128x128)
      const int r = f >> 4, cc = f & 15;
      const int col = cc * 8;
      const int head = h0 + (col >> 6), d = col & 63;
      float4 vv = *(const float4*)(lc + r * 132 + col);
      *(float4*)(O + (((size_t)(b * 16 + head)) << 16) + (t0 + r) * 64 + d) = vv;
    }
  } else {
    // transposed epilogue: lc[col][row]
    #pragma unroll
    for (int mi = 0; mi < 4; mi++)
      #pragma unroll
      for (int ni = 0; ni < 2; ni++)
        #pragma unroll
        for (int rr = 0; rr < 4; rr++) {
          const int row = wr * 64 + (mi >> 1) * 32 + (mi & 1) * 16 + lq * 4 + rr;
          const int col = wc * 32 + ni * 16 + lr;
          lc[col * 132 + row] = f2bf_s(acc[mi][ni][rr] + bqkv[col0 + col]);
        }
    __syncthreads();
    #pragma unroll
    for (int c = 0; c < 4; c++) {
      const int f = tid + 512 * c;
      const int dl = f >> 4, tc = f & 15;       // local d 0..127, t-chunk
      const int head = h0 + (dl >> 6), d = dl & 63;
      float4 vv = *(const float4*)(lc + dl * 132 + tc * 8);
      *(float4*)(Vt + (((size_t)(b * 16 + head)) << 16) + (size_t)d * 1024 +
                 t0 + tc * 8) = vv;
    }
  }
}

// ---- tail V sums: TV[hb][qt][d] = sum_{t >= (qt+1)*128} Vt[hb][d][t] ----
__global__ __launch_bounds__(256) void k_tailv(const __hip_bfloat16* __restrict__ Vt,
                                               float* __restrict__ TV) {
  __shared__ float ts[8][64];
  const int hb = blockIdx.x, tid = threadIdx.x;
  const __hip_bfloat16* Vh = Vt + ((size_t)hb << 16);
  for (int w = tid; w < 512; w += 256) {
    const int kt = w >> 6, d = w & 63;
    const short* p = (const short*)(Vh + (size_t)d * 1024 + kt * 128);
    float s = 0.f;
    for (int j = 0; j < 128; j += 8) {
      bf16x8 v = *(const bf16x8*)(p + j);
      #pragma unroll
      for (int e = 0; e < 8; e++) s += bf2f(v[e]);
    }
    ts[kt][d] = s;
  }
  __syncthreads();
  for (int w = tid; w < 512; w += 256) {
    const int qt = w >> 6, d = w & 63;
    float s = 0.f;
    for (int kt = qt + 1; kt < 8; kt++) s += ts[kt][d];
    TV[((size_t)hb * 8 + qt) * 64 + d] = s;
  }
}

// ---- fused attention: one block = (64 q-rows, one head); 1024 blocks ----
// Separate lK/lV buffers; 2 barriers per kt; K(kt+1) prefetched alongside
// V(kt) so its latency hides under softmax+PV; setprio on MFMA clusters.
__global__ __launch_bounds__(256, 3) void k_attn(
    const __hip_bfloat16* __restrict__ Q, const __hip_bfloat16* __restrict__ K,
    const __hip_bfloat16* __restrict__ Vt, const float* __restrict__ TV,
    float* __restrict__ y) {
  __shared__ short lp[64 * 130];   // P-tile (padded)
  __shared__ short lK[128 * 64];   // K-tile, swizzled
  __shared__ short lV[128 * 64];   // V^T-tile, swizzled
  const int hb = blockIdx.y;
  const int j = (blockIdx.y & 32) ? (15 - (int)blockIdx.x) : (int)blockIdx.x;
  const int q0 = j * 64;
  const int nkt = (j >> 1) + 1;    // K-tiles (128 wide) to compute
  const int tid = threadIdx.x, lane = tid & 63, wave = tid >> 6;
  const int lr = lane & 15, lq = lane >> 4;
  const int wm = wave * 16;        // wave owns q-rows [q0+wm, q0+wm+16)
  const __hip_bfloat16* Qh = Q + ((size_t)hb << 16);
  const __hip_bfloat16* Kh = K + ((size_t)hb << 16);
  const __hip_bfloat16* Vh = Vt + ((size_t)hb << 16);

  // Q A-frags: direct global loads (rows q0+wm+lr, cols s*32+lq*8)
  bf16x8 qf[2];
  #pragma unroll
  for (int s = 0; s < 2; s++)
    qf[s] = *(const bf16x8*)((const short*)Qh +
                             (size_t)(q0 + wm + lr) * 64 + s * 32 + lq * 8);

  f32x4 oacc[4] = {};
  float mrow[4], lrow[4];
  #pragma unroll
  for (int r = 0; r < 4; r++) { mrow[r] = -1e30f; lrow[r] = 0.f; }

  // prologue: stage K(0)
  for (int c = tid; c < 1024; c += 256)
    stage16(Kh + (size_t)(c >> 3) * 64 + (((c & 7) ^ ((c >> 3) & 7)) << 3),
            lK + c * 8);
  __syncthreads();  // K(0) visible

  for (int kt = 0; kt < nkt; kt++) {
    const int k0 = kt * 128;
    // ---- QK^T from lK ----
    f32x4 sacc[8] = {};
    __builtin_amdgcn_s_setprio(1);
    #pragma unroll
    for (int s = 0; s < 2; s++) {
      bf16x8 bf[8];
      #pragma unroll
      for (int ni = 0; ni < 8; ni++) {
        const int n = ni * 16 + lr;
        bf[ni] = *(const bf16x8*)(lK + n * 64 + (((s * 4 + lq) ^ (n & 7)) << 3));
      }
      #pragma unroll
      for (int ni = 0; ni < 8; ni++)
        sacc[ni] = __builtin_amdgcn_mfma_f32_16x16x32_bf16(
            qf[s], bf[ni], sacc[ni], 0, 0, 0);
    }
    __builtin_amdgcn_s_setprio(0);
    __syncthreads();  // barA: lK frag reads + prev PV's lp/lV reads done
    // ---- V(kt) + K(kt+1) DMA (latency hides under softmax below) ----
    for (int c = tid; c < 1024; c += 256)
      stage16(Vh + (size_t)(c >> 4) * 1024 + k0 + (((c & 15) ^ ((c >> 4) & 15)) << 3),
              lV + c * 8);
    if (kt + 1 < nkt) {
      const int k1 = k0 + 128;
      for (int c = tid; c < 1024; c += 256)
        stage16(Kh + (size_t)(k1 + (c >> 3)) * 64 + (((c & 7) ^ ((c >> 3) & 7)) << 3),
                lK + c * 8);
    }
    // ---- online softmax, base-2 domain ----
    const bool last = (kt == nkt - 1);
    #pragma unroll
    for (int r = 0; r < 4; r++) {
      const int grow = q0 + wm + lq * 4 + r;   // global q row
      float tmax = -1e30f;
      #pragma unroll
      for (int ni = 0; ni < 8; ni++) {
        float v = sacc[ni][r];
        if (last && (k0 + ni * 16 + lr) > grow) v = MASK2;
        sacc[ni][r] = v;
        tmax = fmaxf(tmax, v);
      }
      #pragma unroll
      for (int msk = 8; msk; msk >>= 1) tmax = fmaxf(tmax, __shfl_xor(tmax, msk));
      const float mn = fmaxf(mrow[r], tmax);
      const float al = __builtin_amdgcn_exp2f(mrow[r] - mn);
      float rs = 0.f;
      #pragma unroll
      for (int ni = 0; ni < 8; ni++) {
        const float pv = __builtin_amdgcn_exp2f(sacc[ni][r] - mn);
        sacc[ni][r] = pv;
        rs += pv;
      }
      #pragma unroll
      for (int msk = 8; msk; msk >>= 1) rs += __shfl_xor(rs, msk);
      mrow[r] = mn;
      lrow[r] = lrow[r] * al + rs;
      #pragma unroll
      for (int ni = 0; ni < 4; ni++) oacc[ni][r] *= al;
    }
    // P -> lp (padded pitch 130)
    #pragma unroll
    for (int r = 0; r < 4; r++) {
      const int row = wm + lq * 4 + r;
      #pragma unroll
      for (int ni = 0; ni < 8; ni++)
        lp[row * 130 + ni * 16 + lr] = f2bf_s(sacc[ni][r]);
    }
    __syncthreads();  // barB: V(kt)+K(kt+1) landed (vmcnt drain) + P visible
    // ---- PV from lp, lV ----
    __builtin_amdgcn_s_setprio(1);
    #pragma unroll
    for (int ks = 0; ks < 4; ks++) {
      bf16x8 pa, vb[4];
      pa = *(const bf16x8*)(lp + (wm + lr) * 130 + ks * 32 + lq * 8);
      #pragma unroll
      for (int ni = 0; ni < 4; ni++) {
        const int d = ni * 16 + lr;
        vb[ni] = *(const bf16x8*)(lV + d * 128 + (((ks * 4 + lq) ^ (d & 15)) << 3));
      }
      #pragma unroll
      for (int ni = 0; ni < 4; ni++)
        oacc[ni] = __builtin_amdgcn_mfma_f32_16x16x32_bf16(
            pa, vb[ni], oacc[ni], 0, 0, 0);
    }
    __builtin_amdgcn_s_setprio(0);
    // no barrier here: next QK reads lK (disjoint from lp/lV); barA covers reuse
  }

  const int b = hb >> 4, h = hb & 15;
  const float cv = (float)(1024 - nkt * 128);
  const float* tv = TV + ((size_t)hb * 8 + (j >> 1)) * 64;
  #pragma unroll
  for (int r = 0; r < 4; r++) {
    const int t = q0 + wm + lq * 4 + r;
    const float tail = __builtin_amdgcn_exp2f(MASK2 - mrow[r]);
    const float inv = 1.f / (lrow[r] + cv * tail);
    #pragma unroll
    for (int ni = 0; ni < 4; ni++) {
      const int d = ni * 16 + lr;
      y[((size_t)(b * 1024 + t) << 10) + h * 64 + d] =
          (oacc[ni][r] + tail * tv[d]) * inv;
    }
  }
}

// ---- MLP1: h2[4096,1024] @ W1t[4096,1024]^T + b1 -> tanh-GELU -> G bf16 ----
// 256x256 tile, grid(16,16), 512 thr, BK=64, 8-phase counted-vmcnt.
// Epilogue: 2 passes of 128 rows (lc 128x264 = 67.6KB).
__global__ __launch_bounds__(512, 2) void k_gemm_mlp1(const __hip_bfloat16* __restrict__ h2,
                                                      const __hip_bfloat16* __restrict__ W1t,
                                                      const float* __restrict__ b1,
                                                      __hip_bfloat16* __restrict__ G) {
  __shared__ alignas(16) short smem[65536];  // 128KB: Ae Ao Be Bo x 16384
  short* Ae = smem;
  short* Ao = smem + 16384;
  short* Be = smem + 32768;
  short* Bo = smem + 49152;
  const int row0 = blockIdx.x * 256, col0 = blockIdx.y * 256;
  const int tid = threadIdx.x, lane = tid & 63, wid = tid >> 6;
  const int lr = lane & 15, lq = lane >> 4;
  const int wr = wid >> 2, wc = wid & 3;
  const __hip_bfloat16* A = h2 + (size_t)row0 * 1024;
  const __hip_bfloat16* Bt = W1t + (size_t)col0 * 1024;

  auto STG = [&](const __hip_bfloat16* src, int k0, int h, short* dst, int SH) {
    #pragma unroll
    for (int ii = 0; ii < 2; ii++) {
      const int f = tid + ii * 512;
      const int rp = f >> 3, P = f & 7;
      const int r = ((rp >> SH) << (SH + 1)) | (h << SH) | (rp & ((1 << SH) - 1));
      const int g = P ^ (r & 7);
      stage16(src + (size_t)r * 1024 + k0 + g * 8, dst + r * 64 + P * 8);
    }
  };

  f32x4 acc[8][4] = {};
  bf16x8 af[4][2], bf[2][2];

  // prologue: E0 (4 parts) + O0.A0, O0.B0; vmcnt(4) retires E0 (FIFO).
  STG(A, 0, 0, Ae, 6);  STG(Bt, 0, 0, Be, 5);
  STG(A, 0, 1, Ae, 6);  STG(Bt, 0, 1, Be, 5);
  STG(A, 64, 0, Ao, 6); STG(Bt, 64, 0, Bo, 5);
  asm volatile("s_waitcnt vmcnt(4)" ::: "memory");
  __syncthreads();

  for (int i = 0; i < 8; ++i) {
    const int kE1 = (i + 1) * 128;       // next even K-tile
    const int kO0 = i * 128 + 64;        // this iter's odd K-tile
    const int kO1 = kE1 + 64;            // next odd K-tile
    const bool more = (i + 1 < 8);
    ph_read<0, 0>(Ae, Be, wr, wc, lr, lq, af, bf);
    STG(A, kO0, 1, Ao, 6);
    ph_sync();
    ph_mfma<0, 0>(acc, af, bf);
    ph_read<0, 1>(Ae, Be, wr, wc, lr, lq, af, bf);
    STG(Bt, kO0, 1, Bo, 5);
    ph_sync();
    ph_mfma<0, 1>(acc, af, bf);
    ph_read<1, 0>(Ae, Be, wr, wc, lr, lq, af, bf);
    if (more) STG(A, kE1, 0, Ae, 6);
    ph_sync();
    ph_mfma<1, 0>(acc, af, bf);
    ph_read<1, 1>(Ae, Be, wr, wc, lr, lq, af, bf);
    if (more) {
      STG(Bt, kE1, 0, Be, 5);
      asm volatile("s_waitcnt vmcnt(4)" ::: "memory");
    } else {
      asm volatile("s_waitcnt vmcnt(0)" ::: "memory");
    }
    ph_sync();
    ph_mfma<1, 1>(acc, af, bf);
    ph_read<0, 0>(Ao, Bo, wr, wc, lr, lq, af, bf);
    if (more) STG(A, kE1, 1, Ae, 6);
    ph_sync();
    ph_mfma<0, 0>(acc, af, bf);
    ph_read<0, 1>(Ao, Bo, wr, wc, lr, lq, af, bf);
    if (more) STG(Bt, kE1, 1, Be, 5);
    ph_sync();
    ph_mfma<0, 1>(acc, af, bf);
    ph_read<1, 0>(Ao, Bo, wr, wc, lr, lq, af, bf);
    if (more) STG(A, kO1, 0, Ao, 6);
    ph_sync();
    ph_mfma<1, 0>(acc, af, bf);
    ph_read<1, 1>(Ao, Bo, wr, wc, lr, lq, af, bf);
    if (more) {
      STG(Bt, kO1, 0, Bo, 5);
      asm volatile("s_waitcnt vmcnt(4)" ::: "memory");
    }
    ph_sync();
    ph_mfma<1, 1>(acc, af, bf);
  }

  // epilogue: tanh-GELU -> bf16 via 2x 128-row lc passes (lc = smem)
  short* lc = smem;                      // 128*264 = 33792 shorts (67.6KB)
  #pragma unroll
  for (int pr = 0; pr < 2; pr++) {
    if (wr == pr) {
      #pragma unroll
      for (int mi = 0; mi < 8; mi++)
        #pragma unroll
        for (int ni = 0; ni < 4; ni++)
          #pragma unroll
          for (int rr = 0; rr < 4; rr++) {
            const int rloc = mi * 16 + lq * 4 + rr;
            const int col = wc * 64 + ni * 16 + lr;
            float v = acc[mi][ni][rr] + b1[col0 + col];
            const float u2 = fminf(v * (2.3022079f + 0.1029434f * v * v), 80.f);
            const float e = __builtin_amdgcn_exp2f(u2);
            v = v * e * __builtin_amdgcn_rcpf(e + 1.f);
            lc[rloc * 264 + col] = f2bf_s(v);
          }
    }
    __syncthreads();
    #pragma unroll
    for (int c = 0; c < 8; c++) {
      const int f = tid + 512 * c;       // 4096 chunks: 128 rows x 32 chunks
      const int r = f >> 5, cc = f & 31;
      float4 vv = *(const float4*)(lc + r * 264 + cc * 8);
      *(float4*)(G + ((size_t)(row0 + pr * 128 + r) << 12) + col0 + cc * 8) = vv;
    }
    __syncthreads();
  }
}

// ---- MLP2: out += G @ W2t^T, NO split-K, NO atomics (RMW epilogue) ----
// 128x128 tile, grid(32,8)=256 blocks, K=4096, 512 thr, BK=64,
// 2 K-tiles/iter (32 iters), 4 phases x 8 MFMA, LDS 64KB.
__global__ __launch_bounds__(512, 2) void k_gemm_mlp2(const __hip_bfloat16* __restrict__ G,
                                                      const __hip_bfloat16* __restrict__ W2t,
                                                      float* __restrict__ out) {
  __shared__ alignas(16) short smem[32768];  // 64KB: Ae Ao Be Bo x 8192
  short* Ae = smem;
  short* Ao = smem + 8192;
  short* Be = smem + 16384;
  short* Bo = smem + 24576;
  const int row0 = blockIdx.x * 128, col0 = blockIdx.y * 128;
  const int tid = threadIdx.x, lane = tid & 63, wid = tid >> 6;
  const int lr = lane & 15, lq = lane >> 4;
  const int wr = wid >> 2, wc = wid & 3;     // 2M x 4N: 64 rows x 32 cols
  const __hip_bfloat16* A = G + (size_t)row0 * 4096;
  const __hip_bfloat16* Bt = W2t + (size_t)col0 * 4096;

  auto STGA = [&](int k0, int h, short* dst) {
    const int rp = tid >> 3, P = tid & 7;    // rp 0-63
    const int r = ((rp >> 5) << 6) | (h << 5) | (rp & 31);
    const int g = P ^ (r & 7);
    stage16(A + (size_t)r * 4096 + k0 + g * 8, dst + r * 64 + P * 8);
  };
  auto STGB = [&](int k0, short* dst) {
    #pragma unroll
    for (int ii = 0; ii < 2; ii++) {
      const int f = tid + ii * 512;
      const int r = f >> 3, P = f & 7;
      const int g = P ^ (r & 7);
      stage16(Bt + (size_t)r * 4096 + k0 + g * 8, dst + r * 64 + P * 8);
    }
  };

  f32x4 acc[4][2] = {};
  bf16x8 af[2][2], bf[2][2];

  auto RDA = [&](const short* pa, int MH) {
    #pragma unroll
    for (int mi2 = 0; mi2 < 2; mi2++)
      #pragma unroll
      for (int ks = 0; ks < 2; ks++) {
        const int r = wr * 64 + MH * 32 + mi2 * 16 + lr;   // bit5 == MH
        af[mi2][ks] = *(const bf16x8*)(pa + r * 64 + (((ks * 4 + lq) ^ (r & 7)) << 3));
      }
  };
  auto RDB = [&](const short* pb) {
    #pragma unroll
    for (int ni = 0; ni < 2; ni++)
      #pragma unroll
      for (int ks = 0; ks < 2; ks++) {
        const int n = wc * 32 + ni * 16 + lr;
        bf[ni][ks] = *(const bf16x8*)(pb + n * 64 + (((ks * 4 + lq) ^ (n & 7)) << 3));
      }
  };

  STGB(0, Be); STGA(0, 0, Ae);
  STGA(0, 1, Ae);
  STGB(64, Bo); STGA(64, 0, Ao);
  asm volatile("s_waitcnt vmcnt(4)" ::: "memory");
  __syncthreads();

  for (int i = 0; i < 32; ++i) {
    const int kE1 = (i + 1) * 128, kO0 = i * 128 + 64, kO1 = kE1 + 64;
    const bool more = (i + 1 < 32);
    RDA(Ae, 0); RDB(Be);
    STGA(kO0, 1, Ao);
    asm volatile("s_waitcnt vmcnt(4)" ::: "memory");
    ph_sync();
    mmh<0>(acc, af, bf);
    RDA(Ae, 1);
    if (more) {
      STGB(kE1, Be); STGA(kE1, 0, Ae);
      asm volatile("s_waitcnt vmcnt(4)" ::: "memory");
    } else {
      asm volatile("s_waitcnt vmcnt(1)" ::: "memory");
    }
    ph_sync();
    mmh<1>(acc, af, bf);
    RDA(Ao, 0); RDB(Bo);
    if (more) {
      STGA(kE1, 1, Ae);
      asm volatile("s_waitcnt vmcnt(4)" ::: "memory");
    } else {
      asm volatile("s_waitcnt vmcnt(0)" ::: "memory");
    }
    ph_sync();
    mmh<0>(acc, af, bf);
    RDA(Ao, 1);
    if (more) {
      STGB(kO1, Bo); STGA(kO1, 0, Ao);
      asm volatile("s_waitcnt vmcnt(4)" ::: "memory");
    }
    ph_sync();
    mmh<1>(acc, af, bf);
  }

  // epilogue: plain RMW (out pre-initialized with x2 + b2 by k_ln)
  #pragma unroll
  for (int mi = 0; mi < 4; mi++)
    #pragma unroll
    for (int ni = 0; ni < 2; ni++)
      #pragma unroll
      for (int rr = 0; rr < 4; rr++) {
        const int grow = row0 + wr * 64 + (mi >> 1) * 32 + (mi & 1) * 16 + lq * 4 + rr;
        const int gcol = col0 + wc * 32 + ni * 16 + lr;
        float* p = out + (((size_t)grow << 10) + gcol);
        *p += acc[mi][ni][rr];
      }
}

extern "C" void kernel_launch(void* const* d_in, const int* in_sizes, int n_in,
                              void* d_out, int out_size, void* d_ws, size_t ws_size,
                              hipStream_t stream) {
  const float* x     = (const float*)d_in[0];
  const float* ln1_g = (const float*)d_in[1];
  const float* ln1_b = (const float*)d_in[2];
  const float* ln2_g = (const float*)d_in[3];
  const float* ln2_b = (const float*)d_in[4];
  const float* Wq    = (const float*)d_in[5];
  const float* bq    = (const float*)d_in[6];
  const float* Wk    = (const float*)d_in[7];
  const float* bk    = (const float*)d_in[8];
  const float* Wv    = (const float*)d_in[9];
  const float* bv    = (const float*)d_in[10];
  const float* W1    = (const float*)d_in[11];
  const float* b1    = (const float*)d_in[12];
  const float* W2    = (const float*)d_in[13];
  const float* b2    = (const float*)d_in[14];
  float* out = (float*)d_out;

  char* p = (char*)d_ws;
  auto alloc = [&](size_t bytes) { char* r = p; p += (bytes + 255) & ~(size_t)255; return r; };
  __hip_bfloat16* wqkv = (__hip_bfloat16*)alloc(3072 * 1024 * 2);
  __hip_bfloat16* w1t  = (__hip_bfloat16*)alloc(4096 * 1024 * 2);
  __hip_bfloat16* w2t  = (__hip_bfloat16*)alloc(1024 * 4096 * 2);
  float*          bqkv = (float*)alloc(3072 * 4);
  __hip_bfloat16* h1   = (__hip_bfloat16*)alloc(4096 * 1024 * 2);
  __hip_bfloat16* Qb   = (__hip_bfloat16*)alloc((size_t)64 * 65536 * 2);  // [64][1024][64]
  __hip_bfloat16* Kb   = (__hip_bfloat16*)alloc((size_t)64 * 65536 * 2);
  __hip_bfloat16* Vt   = (__hip_bfloat16*)alloc((size_t)64 * 65536 * 2);  // [64][64][1024]
  float*          TV   = (float*)alloc((size_t)64 * 8 * 64 * 4);
  float*          yb   = (float*)alloc((size_t)4096 * 1024 * 4);
  __hip_bfloat16* h2   = (__hip_bfloat16*)alloc(4096 * 1024 * 2);
  __hip_bfloat16* G    = (__hip_bfloat16*)alloc((size_t)4096 * 4096 * 2);
  (void)ws_size; (void)in_sizes; (void)n_in; (void)out_size;

  const dim3 b256(256), bt(32, 8);
  k_prep<<<11276, bt, 0, stream>>>(Wq, Wk, Wv, wqkv, W1, w1t, W2, w2t,
                                   bq, bk, bv, bqkv);

  k_ln<<<4096, b256, 0, stream>>>(x, nullptr, ln1_g, ln1_b, h1, nullptr, nullptr);
  k_gemm_qkv<<<dim3(32, 24), dim3(512), 0, stream>>>(h1, wqkv, bqkv, Qb, Kb, Vt);
  k_tailv<<<64, b256, 0, stream>>>(Vt, TV);
  k_attn<<<dim3(16, 64), b256, 0, stream>>>(Qb, Kb, Vt, TV, yb);

  k_ln<<<4096, b256, 0, stream>>>(x, yb, ln2_g, ln2_b, h2, b2, out);
  k_gemm_mlp1<<<dim3(16, 16), dim3(512), 0, stream>>>(h2, w1t, b1, G);
  k_gemm_mlp2<<<dim3(32, 8), dim3(512), 0, stream>>>(G, w2t, out);
}

// Round 15
// 285.114 us; speedup vs baseline: 1.0734x; 1.0635x over previous
//
#include <hip/hip_runtime.h>
#include <hip/hip_bf16.h>
#include <math.h>

// Transformer block (pre-LN attn + MLP), B=4 T=1024 H=1024 K=16 HD=64.
// R25: attn restructured. R24 exposed attn at 46.8us with MfmaUtil 7%,
// 65% idle, and 1.77M LDS bank conflicts (only kernel with any).
// (1) lp P-tile: pitch 130 -> 128 with chunk-XOR swizzle c^(row&15) on
//     BOTH write and read (read bank pattern becomes the verified-uniform
//     K/V pattern; old pitch-130 b128 reads were (lr+4lq)%32, ~4-way).
// (2) 128-row q-tiles, 512 thr / 8 waves, grid(8,64)=512 blocks, LDS 64KB
//     -> 2 blocks/CU = 16 waves/CU (was 12): halves K/V DMA + barriers
//     per q-row. nkt=j+1, tv idx=j, cv=1024-nkt*128 (re-derived).
// GEMMs unchanged from R24 (counted-vmcnt phase loops; mlp1 256x256
// 8-phase 2-pass epilogue; mlp2 128x128 RMW; qkv 128x128 + scatter;
// fused k_prep). No XCD swizzle (R23/R24 A/B: harmful on this part).
// Attention math: flash-style, exp2-domain softmax (scale folded into Q);
// masked logits FILLED with 1e-9; fully-masked K-tiles contribute
// exp(1e-9-m)*suffixV analytically (TV precomputed).

typedef __attribute__((ext_vector_type(8))) short bf16x8;
typedef __attribute__((ext_vector_type(4))) float f32x4;

#define DEVINL __device__ __forceinline__

#define LOG2E_SCALE 0.18033688f      /* 0.125 * log2(e) */
#define MASK2 1.4426950408889634e-9f /* 1e-9 * log2(e) */

DEVINL void stage16(const __hip_bfloat16* g, short* l) {
  __builtin_amdgcn_global_load_lds(
      (const __attribute__((address_space(1))) unsigned int*)g,
      (__attribute__((address_space(3))) unsigned int*)l, 16, 0, 0);
}

DEVINL float bf2f(short u) {
  unsigned x = ((unsigned)(unsigned short)u) << 16;
  float f; __builtin_memcpy(&f, &x, 4); return f;
}

DEVINL short f2bf_s(float f) {
  __hip_bfloat16 h = __float2bfloat16(f);
  short s; __builtin_memcpy(&s, &h, 2); return s;
}

DEVINL float block_sum(float v, float* sb) {
  #pragma unroll
  for (int o = 32; o; o >>= 1) v += __shfl_down(v, o);
  const int lane = threadIdx.x & 63, w = threadIdx.x >> 6;
  if (lane == 0) sb[w] = v;
  __syncthreads();
  float r = sb[0] + sb[1] + sb[2] + sb[3];
  __syncthreads();
  return r;
}

// ======== shared phase-schedule helpers ========
DEVINL void ph_sync() {
  __builtin_amdgcn_s_barrier();
  asm volatile("s_waitcnt lgkmcnt(0)" ::: "memory");
  __builtin_amdgcn_sched_barrier(0);
}

// 8-MFMA phase (acc[4][2]; af = A-half MH, bf = 2 N-frags) — mlp2/qkv shape
template<int MH>
DEVINL void mmh(f32x4 (&acc)[4][2], bf16x8 (&af)[2][2], bf16x8 (&bf)[2][2]) {
  __builtin_amdgcn_s_setprio(1);
  #pragma unroll
  for (int mi2 = 0; mi2 < 2; mi2++)
    #pragma unroll
    for (int ni = 0; ni < 2; ni++)
      #pragma unroll
      for (int ks = 0; ks < 2; ks++)
        acc[MH * 2 + mi2][ni] = __builtin_amdgcn_mfma_f32_16x16x32_bf16(
            af[mi2][ks], bf[ni][ks], acc[MH * 2 + mi2][ni], 0, 0, 0);
  __builtin_amdgcn_s_setprio(0);
  __builtin_amdgcn_s_barrier();
}

// 16-MFMA phase for mlp1 (acc[8][4])
template<int MH, int NH>
DEVINL void ph_read(const short* pa, const short* pb, int wr, int wc,
                    int lr, int lq, bf16x8 (&af)[4][2], bf16x8 (&bf)[2][2]) {
  if (NH == 0) {
    #pragma unroll
    for (int mi2 = 0; mi2 < 4; mi2++)
      #pragma unroll
      for (int ks = 0; ks < 2; ks++) {
        const int r = wr * 128 + MH * 64 + mi2 * 16 + lr;
        af[mi2][ks] = *(const bf16x8*)(pa + r * 64 + (((ks * 4 + lq) ^ (r & 7)) << 3));
      }
  }
  #pragma unroll
  for (int ni2 = 0; ni2 < 2; ni2++)
    #pragma unroll
    for (int ks = 0; ks < 2; ks++) {
      const int n = wc * 64 + NH * 32 + ni2 * 16 + lr;
      bf[ni2][ks] = *(const bf16x8*)(pb + n * 64 + (((ks * 4 + lq) ^ (n & 7)) << 3));
    }
}

template<int MH, int NH>
DEVINL void ph_mfma(f32x4 (&acc)[8][4], bf16x8 (&af)[4][2], bf16x8 (&bf)[2][2]) {
  __builtin_amdgcn_s_setprio(1);
  #pragma unroll
  for (int mi2 = 0; mi2 < 4; mi2++)
    #pragma unroll
    for (int ni2 = 0; ni2 < 2; ni2++)
      #pragma unroll
      for (int ks = 0; ks < 2; ks++)
        acc[MH * 4 + mi2][NH * 2 + ni2] = __builtin_amdgcn_mfma_f32_16x16x32_bf16(
            af[mi2][ks], bf[ni2][ks], acc[MH * 4 + mi2][NH * 2 + ni2], 0, 0, 0);
  __builtin_amdgcn_s_setprio(0);
  __builtin_amdgcn_s_barrier();
}

// ---- fused prep: W transposes (f32->bf16) + bias pack, one launch ----
__global__ __launch_bounds__(256) void k_prep(
    const float* __restrict__ Wq, const float* __restrict__ Wk,
    const float* __restrict__ Wv, __hip_bfloat16* __restrict__ wqkv,
    const float* __restrict__ W1, __hip_bfloat16* __restrict__ w1t,
    const float* __restrict__ W2, __hip_bfloat16* __restrict__ w2t,
    const float* __restrict__ bq, const float* __restrict__ bk,
    const float* __restrict__ bv, float* __restrict__ bqkv) {
  __shared__ float tile[32][33];
  const int bid = blockIdx.x;
  const int tx = threadIdx.x, ty = threadIdx.y;  // (32,8)
  const float* src; __hip_bfloat16* dst;
  int c0, r0, C, dOff, dPitch;
  if (bid < 3072) {
    const int z = bid >> 10, rem = bid & 1023;
    src = z == 0 ? Wq : (z == 1 ? Wk : Wv); dst = wqkv;
    c0 = (rem & 31) * 32; r0 = (rem >> 5) * 32;
    C = 1024; dOff = z << 10; dPitch = 1024;
  } else if (bid < 7168) {
    const int rem = bid - 3072;
    src = W1; dst = w1t;
    c0 = (rem & 127) * 32; r0 = (rem >> 7) * 32;
    C = 4096; dOff = 0; dPitch = 1024;
  } else if (bid < 11264) {
    const int rem = bid - 7168;
    src = W2; dst = w2t;
    c0 = (rem & 31) * 32; r0 = (rem >> 5) * 32;
    C = 1024; dOff = 0; dPitch = 4096;
  } else {
    const int i = (bid - 11264) * 256 + ty * 32 + tx;
    if (i < 3072)
      bqkv[i] = i < 1024 ? bq[i] : (i < 2048 ? bk[i - 1024] : bv[i - 2048]);
    return;
  }
  #pragma unroll
  for (int i = 0; i < 32; i += 8)
    tile[ty + i][tx] = src[(size_t)(r0 + ty + i) * C + c0 + tx];
  __syncthreads();
  #pragma unroll
  for (int i = 0; i < 32; i += 8)
    dst[(size_t)(c0 + ty + i + dOff) * dPitch + r0 + tx] =
        __float2bfloat16(tile[tx][ty + i]);
}

// ---- LayerNorm (+residual add; optionally init out = x2 + b2) ----
__global__ __launch_bounds__(256) void k_ln(const float* __restrict__ x,
                                            const float* __restrict__ y,
                                            const float* __restrict__ g,
                                            const float* __restrict__ bb,
                                            __hip_bfloat16* __restrict__ o,
                                            const float* __restrict__ badd,
                                            float* __restrict__ oinit) {
  __shared__ float sb[4];
  const int t = threadIdx.x;
  const size_t base = (size_t)blockIdx.x * 1024 + t * 4;
  const int c = t * 4;
  float4 xv = *(const float4*)(x + base);
  if (y) {
    float4 yv = *(const float4*)(y + base);
    xv.x += yv.x; xv.y += yv.y; xv.z += yv.z; xv.w += yv.w;
    float4 ov;
    ov.x = xv.x + badd[c + 0]; ov.y = xv.y + badd[c + 1];
    ov.z = xv.z + badd[c + 2]; ov.w = xv.w + badd[c + 3];
    *(float4*)(oinit + base) = ov;
  }
  const float mu = block_sum(xv.x + xv.y + xv.z + xv.w, sb) * (1.f / 1024.f);
  const float dx = xv.x - mu, dy = xv.y - mu, dz = xv.z - mu, dw = xv.w - mu;
  const float var = block_sum(dx * dx + dy * dy + dz * dz + dw * dw, sb) * (1.f / 1024.f);
  const float rs = rsqrtf(var + 1e-5f);
  o[base + 0] = __float2bfloat16(dx * rs * g[c + 0] + bb[c + 0]);
  o[base + 1] = __float2bfloat16(dy * rs * g[c + 1] + bb[c + 1]);
  o[base + 2] = __float2bfloat16(dz * rs * g[c + 2] + bb[c + 2]);
  o[base + 3] = __float2bfloat16(dw * rs * g[c + 3] + bb[c + 3]);
}

// ---- QKV GEMM: h1[4096,1024] @ Wqkv_t[3072,1024]^T, 4-phase ----
__global__ __launch_bounds__(512, 2) void k_gemm_qkv(
    const __hip_bfloat16* __restrict__ h1, const __hip_bfloat16* __restrict__ Wt,
    const float* __restrict__ bqkv, __hip_bfloat16* __restrict__ Q,
    __hip_bfloat16* __restrict__ K, __hip_bfloat16* __restrict__ Vt) {
  __shared__ alignas(16) short smem[32768];  // 64KB: Ae Ao Be Bo x 8192
  short* Ae = smem;
  short* Ao = smem + 8192;
  short* Be = smem + 16384;
  short* Bo = smem + 24576;
  const int row0 = blockIdx.x * 128, col0 = blockIdx.y * 128;
  const int tid = threadIdx.x, lane = tid & 63, wid = tid >> 6;
  const int lr = lane & 15, lq = lane >> 4;
  const int wr = wid >> 2, wc = wid & 3;     // 2M x 4N: 64 rows x 32 cols
  const __hip_bfloat16* A = h1 + (size_t)row0 * 1024;
  const __hip_bfloat16* Bt = Wt + (size_t)col0 * 1024;

  auto STGA = [&](int k0, int h, short* dst) {
    const int rp = tid >> 3, P = tid & 7;    // rp 0-63
    const int r = ((rp >> 5) << 6) | (h << 5) | (rp & 31);
    const int g = P ^ (r & 7);
    stage16(A + (size_t)r * 1024 + k0 + g * 8, dst + r * 64 + P * 8);
  };
  auto STGB = [&](int k0, short* dst) {
    #pragma unroll
    for (int ii = 0; ii < 2; ii++) {
      const int f = tid + ii * 512;
      const int r = f >> 3, P = f & 7;
      const int g = P ^ (r & 7);
      stage16(Bt + (size_t)r * 1024 + k0 + g * 8, dst + r * 64 + P * 8);
    }
  };

  f32x4 acc[4][2] = {};
  bf16x8 af[2][2], bf[2][2];

  auto RDA = [&](const short* pa, int MH) {
    #pragma unroll
    for (int mi2 = 0; mi2 < 2; mi2++)
      #pragma unroll
      for (int ks = 0; ks < 2; ks++) {
        const int r = wr * 64 + MH * 32 + mi2 * 16 + lr;   // bit5 == MH
        af[mi2][ks] = *(const bf16x8*)(pa + r * 64 + (((ks * 4 + lq) ^ (r & 7)) << 3));
      }
  };
  auto RDB = [&](const short* pb) {
    #pragma unroll
    for (int ni = 0; ni < 2; ni++)
      #pragma unroll
      for (int ks = 0; ks < 2; ks++) {
        const int n = wc * 32 + ni * 16 + lr;
        bf[ni][ks] = *(const bf16x8*)(pb + n * 64 + (((ks * 4 + lq) ^ (n & 7)) << 3));
      }
  };

  STGB(0, Be); STGA(0, 0, Ae);
  STGA(0, 1, Ae);
  STGB(64, Bo); STGA(64, 0, Ao);
  asm volatile("s_waitcnt vmcnt(4)" ::: "memory");
  __syncthreads();

  for (int i = 0; i < 8; ++i) {
    const int kE1 = (i + 1) * 128, kO0 = i * 128 + 64, kO1 = kE1 + 64;
    const bool more = (i + 1 < 8);
    RDA(Ae, 0); RDB(Be);
    STGA(kO0, 1, Ao);
    asm volatile("s_waitcnt vmcnt(4)" ::: "memory");
    ph_sync();
    mmh<0>(acc, af, bf);
    RDA(Ae, 1);
    if (more) {
      STGB(kE1, Be); STGA(kE1, 0, Ae);
      asm volatile("s_waitcnt vmcnt(4)" ::: "memory");
    } else {
      asm volatile("s_waitcnt vmcnt(1)" ::: "memory");
    }
    ph_sync();
    mmh<1>(acc, af, bf);
    RDA(Ao, 0); RDB(Bo);
    if (more) {
      STGA(kE1, 1, Ae);
      asm volatile("s_waitcnt vmcnt(4)" ::: "memory");
    } else {
      asm volatile("s_waitcnt vmcnt(0)" ::: "memory");
    }
    ph_sync();
    mmh<0>(acc, af, bf);
    RDA(Ao, 1);
    if (more) {
      STGB(kO1, Bo); STGA(kO1, 0, Ao);
      asm volatile("s_waitcnt vmcnt(4)" ::: "memory");
    }
    ph_sync();
    mmh<1>(acc, af, bf);
  }

  // ---- Q/K/V scatter epilogue ----
  const int which = col0 >> 10;                 // uniform: 0=Q 1=K 2=V
  const int h0 = (col0 & 1023) >> 6;
  const int b = row0 >> 10, t0 = row0 & 1023;
  short* lc = smem;                             // 128*132 = 16896 shorts
  if (which < 2) {
    const float qs = (which == 0) ? LOG2E_SCALE : 1.f;
    #pragma unroll
    for (int mi = 0; mi < 4; mi++)
      #pragma unroll
      for (int ni = 0; ni < 2; ni++)
        #pragma unroll
        for (int rr = 0; rr < 4; rr++) {
          const int row = wr * 64 + (mi >> 1) * 32 + (mi & 1) * 16 + lq * 4 + rr;
          const int col = wc * 32 + ni * 16 + lr;
          lc[row * 132 + col] = f2bf_s((acc[mi][ni][rr] + bqkv[col0 + col]) * qs);
        }
    __syncthreads();
    __hip_bfloat16* O = which == 0 ? Q : K;
    #pragma unroll
    for (int c = 0; c < 4; c++) {
      const int f = tid + 512 * c;              // 2048 16B-chunks (128x128)
      const int r = f >> 4, cc = f & 15;
      const int col = cc * 8;
      const int head = h0 + (col >> 6), d = col & 63;
      float4 vv = *(const float4*)(lc + r * 132 + col);
      *(float4*)(O + (((size_t)(b * 16 + head)) << 16) + (t0 + r) * 64 + d) = vv;
    }
  } else {
    // transposed epilogue: lc[col][row]
    #pragma unroll
    for (int mi = 0; mi < 4; mi++)
      #pragma unroll
      for (int ni = 0; ni < 2; ni++)
        #pragma unroll
        for (int rr = 0; rr < 4; rr++) {
          const int row = wr * 64 + (mi >> 1) * 32 + (mi & 1) * 16 + lq * 4 + rr;
          const int col = wc * 32 + ni * 16 + lr;
          lc[col * 132 + row] = f2bf_s(acc[mi][ni][rr] + bqkv[col0 + col]);
        }
    __syncthreads();
    #pragma unroll
    for (int c = 0; c < 4; c++) {
      const int f = tid + 512 * c;
      const int dl = f >> 4, tc = f & 15;       // local d 0..127, t-chunk
      const int head = h0 + (dl >> 6), d = dl & 63;
      float4 vv = *(const float4*)(lc + dl * 132 + tc * 8);
      *(float4*)(Vt + (((size_t)(b * 16 + head)) << 16) + (size_t)d * 1024 +
                 t0 + tc * 8) = vv;
    }
  }
}

// ---- tail V sums: TV[hb][qt][d] = sum_{t >= (qt+1)*128} Vt[hb][d][t] ----
__global__ __launch_bounds__(256) void k_tailv(const __hip_bfloat16* __restrict__ Vt,
                                               float* __restrict__ TV) {
  __shared__ float ts[8][64];
  const int hb = blockIdx.x, tid = threadIdx.x;
  const __hip_bfloat16* Vh = Vt + ((size_t)hb << 16);
  for (int w = tid; w < 512; w += 256) {
    const int kt = w >> 6, d = w & 63;
    const short* p = (const short*)(Vh + (size_t)d * 1024 + kt * 128);
    float s = 0.f;
    for (int j = 0; j < 128; j += 8) {
      bf16x8 v = *(const bf16x8*)(p + j);
      #pragma unroll
      for (int e = 0; e < 8; e++) s += bf2f(v[e]);
    }
    ts[kt][d] = s;
  }
  __syncthreads();
  for (int w = tid; w < 512; w += 256) {
    const int qt = w >> 6, d = w & 63;
    float s = 0.f;
    for (int kt = qt + 1; kt < 8; kt++) s += ts[kt][d];
    TV[((size_t)hb * 8 + qt) * 64 + d] = s;
  }
}

// ---- fused attention: one block = (128 q-rows, one head); 512 blocks ----
// R25: 512 thr / 8 waves (wave owns 16 q-rows), LDS 64KB -> 2 blocks/CU;
// lp chunk-XOR swizzled (pitch 128, c^(row&15) both sides). Separate
// lK/lV; 2 barriers per kt; K(kt+1) prefetch hidden under softmax;
// setprio on MFMA clusters.
__global__ __launch_bounds__(512, 2) void k_attn(
    const __hip_bfloat16* __restrict__ Q, const __hip_bfloat16* __restrict__ K,
    const __hip_bfloat16* __restrict__ Vt, const float* __restrict__ TV,
    float* __restrict__ y) {
  __shared__ short lp[128 * 128];  // P-tile, chunk-XOR swizzled (32KB)
  __shared__ short lK[128 * 64];   // K-tile, swizzled (16KB)
  __shared__ short lV[128 * 64];   // V^T-tile, swizzled (16KB)
  const int hb = blockIdx.y;
  const int j = (blockIdx.y & 32) ? (7 - (int)blockIdx.x) : (int)blockIdx.x;
  const int q0 = j * 128;
  const int nkt = j + 1;           // K-tiles (128 wide) to compute
  const int tid = threadIdx.x, lane = tid & 63, wave = tid >> 6;
  const int lr = lane & 15, lq = lane >> 4;
  const int wm = wave * 16;        // wave owns q-rows [q0+wm, q0+wm+16)
  const __hip_bfloat16* Qh = Q + ((size_t)hb << 16);
  const __hip_bfloat16* Kh = K + ((size_t)hb << 16);
  const __hip_bfloat16* Vh = Vt + ((size_t)hb << 16);

  // Q A-frags: direct global loads (rows q0+wm+lr, cols s*32+lq*8)
  bf16x8 qf[2];
  #pragma unroll
  for (int s = 0; s < 2; s++)
    qf[s] = *(const bf16x8*)((const short*)Qh +
                             (size_t)(q0 + wm + lr) * 64 + s * 32 + lq * 8);

  f32x4 oacc[4] = {};
  float mrow[4], lrow[4];
  #pragma unroll
  for (int r = 0; r < 4; r++) { mrow[r] = -1e30f; lrow[r] = 0.f; }

  // prologue: stage K(0)  (1024 chunks, 512 threads -> 2 iters)
  for (int c = tid; c < 1024; c += 512)
    stage16(Kh + (size_t)(c >> 3) * 64 + (((c & 7) ^ ((c >> 3) & 7)) << 3),
            lK + c * 8);
  __syncthreads();  // K(0) visible

  for (int kt = 0; kt < nkt; kt++) {
    const int k0 = kt * 128;
    // ---- QK^T from lK ----
    f32x4 sacc[8] = {};
    __builtin_amdgcn_s_setprio(1);
    #pragma unroll
    for (int s = 0; s < 2; s++) {
      bf16x8 bf[8];
      #pragma unroll
      for (int ni = 0; ni < 8; ni++) {
        const int n = ni * 16 + lr;
        bf[ni] = *(const bf16x8*)(lK + n * 64 + (((s * 4 + lq) ^ (n & 7)) << 3));
      }
      #pragma unroll
      for (int ni = 0; ni < 8; ni++)
        sacc[ni] = __builtin_amdgcn_mfma_f32_16x16x32_bf16(
            qf[s], bf[ni], sacc[ni], 0, 0, 0);
    }
    __builtin_amdgcn_s_setprio(0);
    __syncthreads();  // barA: lK frag reads + prev PV's lp/lV reads done
    // ---- V(kt) + K(kt+1) DMA (latency hides under softmax below) ----
    for (int c = tid; c < 1024; c += 512)
      stage16(Vh + (size_t)(c >> 4) * 1024 + k0 + (((c & 15) ^ ((c >> 4) & 15)) << 3),
              lV + c * 8);
    if (kt + 1 < nkt) {
      const int k1 = k0 + 128;
      for (int c = tid; c < 1024; c += 512)
        stage16(Kh + (size_t)(k1 + (c >> 3)) * 64 + (((c & 7) ^ ((c >> 3) & 7)) << 3),
                lK + c * 8);
    }
    // ---- online softmax, base-2 domain ----
    const bool last = (kt == nkt - 1);
    #pragma unroll
    for (int r = 0; r < 4; r++) {
      const int grow = q0 + wm + lq * 4 + r;   // global q row
      float tmax = -1e30f;
      #pragma unroll
      for (int ni = 0; ni < 8; ni++) {
        float v = sacc[ni][r];
        if (last && (k0 + ni * 16 + lr) > grow) v = MASK2;
        sacc[ni][r] = v;
        tmax = fmaxf(tmax, v);
      }
      #pragma unroll
      for (int msk = 8; msk; msk >>= 1) tmax = fmaxf(tmax, __shfl_xor(tmax, msk));
      const float mn = fmaxf(mrow[r], tmax);
      const float al = __builtin_amdgcn_exp2f(mrow[r] - mn);
      float rs = 0.f;
      #pragma unroll
      for (int ni = 0; ni < 8; ni++) {
        const float pv = __builtin_amdgcn_exp2f(sacc[ni][r] - mn);
        sacc[ni][r] = pv;
        rs += pv;
      }
      #pragma unroll
      for (int msk = 8; msk; msk >>= 1) rs += __shfl_xor(rs, msk);
      mrow[r] = mn;
      lrow[r] = lrow[r] * al + rs;
      #pragma unroll
      for (int ni = 0; ni < 4; ni++) oacc[ni][r] *= al;
    }
    // P -> lp (chunk-XOR swizzled: elem (row,col) at
    // row*128 + ((col>>3 ^ (row&15))<<3) + (col&7))
    #pragma unroll
    for (int r = 0; r < 4; r++) {
      const int row = wm + lq * 4 + r;
      #pragma unroll
      for (int ni = 0; ni < 8; ni++) {
        const int col = ni * 16 + lr;
        lp[row * 128 + (((col >> 3) ^ (row & 15)) << 3) + (col & 7)] =
            f2bf_s(sacc[ni][r]);
      }
    }
    __syncthreads();  // barB: V(kt)+K(kt+1) landed (vmcnt drain) + P visible
    // ---- PV from lp, lV ----
    __builtin_amdgcn_s_setprio(1);
    #pragma unroll
    for (int ks = 0; ks < 4; ks++) {
      bf16x8 pa, vb[4];
      {
        const int row = wm + lr;
        pa = *(const bf16x8*)(lp + row * 128 +
                              (((ks * 4 + lq) ^ (row & 15)) << 3));
      }
      #pragma unroll
      for (int ni = 0; ni < 4; ni++) {
        const int d = ni * 16 + lr;
        vb[ni] = *(const bf16x8*)(lV + d * 128 + (((ks * 4 + lq) ^ (d & 15)) << 3));
      }
      #pragma unroll
      for (int ni = 0; ni < 4; ni++)
        oacc[ni] = __builtin_amdgcn_mfma_f32_16x16x32_bf16(
            pa, vb[ni], oacc[ni], 0, 0, 0);
    }
    __builtin_amdgcn_s_setprio(0);
    // no barrier here: next QK reads lK (disjoint from lp/lV); barA covers reuse
  }

  const int b = hb >> 4, h = hb & 15;
  const float cv = (float)(1024 - nkt * 128);
  const float* tv = TV + ((size_t)hb * 8 + j) * 64;
  #pragma unroll
  for (int r = 0; r < 4; r++) {
    const int t = q0 + wm + lq * 4 + r;
    const float tail = __builtin_amdgcn_exp2f(MASK2 - mrow[r]);
    const float inv = 1.f / (lrow[r] + cv * tail);
    #pragma unroll
    for (int ni = 0; ni < 4; ni++) {
      const int d = ni * 16 + lr;
      y[((size_t)(b * 1024 + t) << 10) + h * 64 + d] =
          (oacc[ni][r] + tail * tv[d]) * inv;
    }
  }
}

// ---- MLP1: h2[4096,1024] @ W1t[4096,1024]^T + b1 -> tanh-GELU -> G bf16 ----
// 256x256 tile, grid(16,16), 512 thr, BK=64, 8-phase counted-vmcnt.
// Epilogue: 2 passes of 128 rows (lc 128x264 = 67.6KB).
__global__ __launch_bounds__(512, 2) void k_gemm_mlp1(const __hip_bfloat16* __restrict__ h2,
                                                      const __hip_bfloat16* __restrict__ W1t,
                                                      const float* __restrict__ b1,
                                                      __hip_bfloat16* __restrict__ G) {
  __shared__ alignas(16) short smem[65536];  // 128KB: Ae Ao Be Bo x 16384
  short* Ae = smem;
  short* Ao = smem + 16384;
  short* Be = smem + 32768;
  short* Bo = smem + 49152;
  const int row0 = blockIdx.x * 256, col0 = blockIdx.y * 256;
  const int tid = threadIdx.x, lane = tid & 63, wid = tid >> 6;
  const int lr = lane & 15, lq = lane >> 4;
  const int wr = wid >> 2, wc = wid & 3;
  const __hip_bfloat16* A = h2 + (size_t)row0 * 1024;
  const __hip_bfloat16* Bt = W1t + (size_t)col0 * 1024;

  auto STG = [&](const __hip_bfloat16* src, int k0, int h, short* dst, int SH) {
    #pragma unroll
    for (int ii = 0; ii < 2; ii++) {
      const int f = tid + ii * 512;
      const int rp = f >> 3, P = f & 7;
      const int r = ((rp >> SH) << (SH + 1)) | (h << SH) | (rp & ((1 << SH) - 1));
      const int g = P ^ (r & 7);
      stage16(src + (size_t)r * 1024 + k0 + g * 8, dst + r * 64 + P * 8);
    }
  };

  f32x4 acc[8][4] = {};
  bf16x8 af[4][2], bf[2][2];

  // prologue: E0 (4 parts) + O0.A0, O0.B0; vmcnt(4) retires E0 (FIFO).
  STG(A, 0, 0, Ae, 6);  STG(Bt, 0, 0, Be, 5);
  STG(A, 0, 1, Ae, 6);  STG(Bt, 0, 1, Be, 5);
  STG(A, 64, 0, Ao, 6); STG(Bt, 64, 0, Bo, 5);
  asm volatile("s_waitcnt vmcnt(4)" ::: "memory");
  __syncthreads();

  for (int i = 0; i < 8; ++i) {
    const int kE1 = (i + 1) * 128;       // next even K-tile
    const int kO0 = i * 128 + 64;        // this iter's odd K-tile
    const int kO1 = kE1 + 64;            // next odd K-tile
    const bool more = (i + 1 < 8);
    ph_read<0, 0>(Ae, Be, wr, wc, lr, lq, af, bf);
    STG(A, kO0, 1, Ao, 6);
    ph_sync();
    ph_mfma<0, 0>(acc, af, bf);
    ph_read<0, 1>(Ae, Be, wr, wc, lr, lq, af, bf);
    STG(Bt, kO0, 1, Bo, 5);
    ph_sync();
    ph_mfma<0, 1>(acc, af, bf);
    ph_read<1, 0>(Ae, Be, wr, wc, lr, lq, af, bf);
    if (more) STG(A, kE1, 0, Ae, 6);
    ph_sync();
    ph_mfma<1, 0>(acc, af, bf);
    ph_read<1, 1>(Ae, Be, wr, wc, lr, lq, af, bf);
    if (more) {
      STG(Bt, kE1, 0, Be, 5);
      asm volatile("s_waitcnt vmcnt(4)" ::: "memory");
    } else {
      asm volatile("s_waitcnt vmcnt(0)" ::: "memory");
    }
    ph_sync();
    ph_mfma<1, 1>(acc, af, bf);
    ph_read<0, 0>(Ao, Bo, wr, wc, lr, lq, af, bf);
    if (more) STG(A, kE1, 1, Ae, 6);
    ph_sync();
    ph_mfma<0, 0>(acc, af, bf);
    ph_read<0, 1>(Ao, Bo, wr, wc, lr, lq, af, bf);
    if (more) STG(Bt, kE1, 1, Be, 5);
    ph_sync();
    ph_mfma<0, 1>(acc, af, bf);
    ph_read<1, 0>(Ao, Bo, wr, wc, lr, lq, af, bf);
    if (more) STG(A, kO1, 0, Ao, 6);
    ph_sync();
    ph_mfma<1, 0>(acc, af, bf);
    ph_read<1, 1>(Ao, Bo, wr, wc, lr, lq, af, bf);
    if (more) {
      STG(Bt, kO1, 0, Bo, 5);
      asm volatile("s_waitcnt vmcnt(4)" ::: "memory");
    }
    ph_sync();
    ph_mfma<1, 1>(acc, af, bf);
  }

  // epilogue: tanh-GELU -> bf16 via 2x 128-row lc passes (lc = smem)
  short* lc = smem;                      // 128*264 = 33792 shorts (67.6KB)
  #pragma unroll
  for (int pr = 0; pr < 2; pr++) {
    if (wr == pr) {
      #pragma unroll
      for (int mi = 0; mi < 8; mi++)
        #pragma unroll
        for (int ni = 0; ni < 4; ni++)
          #pragma unroll
          for (int rr = 0; rr < 4; rr++) {
            const int rloc = mi * 16 + lq * 4 + rr;
            const int col = wc * 64 + ni * 16 + lr;
            float v = acc[mi][ni][rr] + b1[col0 + col];
            const float u2 = fminf(v * (2.3022079f + 0.1029434f * v * v), 80.f);
            const float e = __builtin_amdgcn_exp2f(u2);
            v = v * e * __builtin_amdgcn_rcpf(e + 1.f);
            lc[rloc * 264 + col] = f2bf_s(v);
          }
    }
    __syncthreads();
    #pragma unroll
    for (int c = 0; c < 8; c++) {
      const int f = tid + 512 * c;       // 4096 chunks: 128 rows x 32 chunks
      const int r = f >> 5, cc = f & 31;
      float4 vv = *(const float4*)(lc + r * 264 + cc * 8);
      *(float4*)(G + ((size_t)(row0 + pr * 128 + r) << 12) + col0 + cc * 8) = vv;
    }
    __syncthreads();
  }
}

// ---- MLP2: out += G @ W2t^T, NO split-K, NO atomics (RMW epilogue) ----
// 128x128 tile, grid(32,8)=256 blocks, K=4096, 512 thr, BK=64,
// 2 K-tiles/iter (32 iters), 4 phases x 8 MFMA, LDS 64KB.
__global__ __launch_bounds__(512, 2) void k_gemm_mlp2(const __hip_bfloat16* __restrict__ G,
                                                      const __hip_bfloat16* __restrict__ W2t,
                                                      float* __restrict__ out) {
  __shared__ alignas(16) short smem[32768];  // 64KB: Ae Ao Be Bo x 8192
  short* Ae = smem;
  short* Ao = smem + 8192;
  short* Be = smem + 16384;
  short* Bo = smem + 24576;
  const int row0 = blockIdx.x * 128, col0 = blockIdx.y * 128;
  const int tid = threadIdx.x, lane = tid & 63, wid = tid >> 6;
  const int lr = lane & 15, lq = lane >> 4;
  const int wr = wid >> 2, wc = wid & 3;     // 2M x 4N: 64 rows x 32 cols
  const __hip_bfloat16* A = G + (size_t)row0 * 4096;
  const __hip_bfloat16* Bt = W2t + (size_t)col0 * 4096;

  auto STGA = [&](int k0, int h, short* dst) {
    const int rp = tid >> 3, P = tid & 7;    // rp 0-63
    const int r = ((rp >> 5) << 6) | (h << 5) | (rp & 31);
    const int g = P ^ (r & 7);
    stage16(A + (size_t)r * 4096 + k0 + g * 8, dst + r * 64 + P * 8);
  };
  auto STGB = [&](int k0, short* dst) {
    #pragma unroll
    for (int ii = 0; ii < 2; ii++) {
      const int f = tid + ii * 512;
      const int r = f >> 3, P = f & 7;
      const int g = P ^ (r & 7);
      stage16(Bt + (size_t)r * 4096 + k0 + g * 8, dst + r * 64 + P * 8);
    }
  };

  f32x4 acc[4][2] = {};
  bf16x8 af[2][2], bf[2][2];

  auto RDA = [&](const short* pa, int MH) {
    #pragma unroll
    for (int mi2 = 0; mi2 < 2; mi2++)
      #pragma unroll
      for (int ks = 0; ks < 2; ks++) {
        const int r = wr * 64 + MH * 32 + mi2 * 16 + lr;   // bit5 == MH
        af[mi2][ks] = *(const bf16x8*)(pa + r * 64 + (((ks * 4 + lq) ^ (r & 7)) << 3));
      }
  };
  auto RDB = [&](const short* pb) {
    #pragma unroll
    for (int ni = 0; ni < 2; ni++)
      #pragma unroll
      for (int ks = 0; ks < 2; ks++) {
        const int n = wc * 32 + ni * 16 + lr;
        bf[ni][ks] = *(const bf16x8*)(pb + n * 64 + (((ks * 4 + lq) ^ (n & 7)) << 3));
      }
  };

  STGB(0, Be); STGA(0, 0, Ae);
  STGA(0, 1, Ae);
  STGB(64, Bo); STGA(64, 0, Ao);
  asm volatile("s_waitcnt vmcnt(4)" ::: "memory");
  __syncthreads();

  for (int i = 0; i < 32; ++i) {
    const int kE1 = (i + 1) * 128, kO0 = i * 128 + 64, kO1 = kE1 + 64;
    const bool more = (i + 1 < 32);
    RDA(Ae, 0); RDB(Be);
    STGA(kO0, 1, Ao);
    asm volatile("s_waitcnt vmcnt(4)" ::: "memory");
    ph_sync();
    mmh<0>(acc, af, bf);
    RDA(Ae, 1);
    if (more) {
      STGB(kE1, Be); STGA(kE1, 0, Ae);
      asm volatile("s_waitcnt vmcnt(4)" ::: "memory");
    } else {
      asm volatile("s_waitcnt vmcnt(1)" ::: "memory");
    }
    ph_sync();
    mmh<1>(acc, af, bf);
    RDA(Ao, 0); RDB(Bo);
    if (more) {
      STGA(kE1, 1, Ae);
      asm volatile("s_waitcnt vmcnt(4)" ::: "memory");
    } else {
      asm volatile("s_waitcnt vmcnt(0)" ::: "memory");
    }
    ph_sync();
    mmh<0>(acc, af, bf);
    RDA(Ao, 1);
    if (more) {
      STGB(kO1, Bo); STGA(kO1, 0, Ao);
      asm volatile("s_waitcnt vmcnt(4)" ::: "memory");
    }
    ph_sync();
    mmh<1>(acc, af, bf);
  }

  // epilogue: plain RMW (out pre-initialized with x2 + b2 by k_ln)
  #pragma unroll
  for (int mi = 0; mi < 4; mi++)
    #pragma unroll
    for (int ni = 0; ni < 2; ni++)
      #pragma unroll
      for (int rr = 0; rr < 4; rr++) {
        const int grow = row0 + wr * 64 + (mi >> 1) * 32 + (mi & 1) * 16 + lq * 4 + rr;
        const int gcol = col0 + wc * 32 + ni * 16 + lr;
        float* p = out + (((size_t)grow << 10) + gcol);
        *p += acc[mi][ni][rr];
      }
}

extern "C" void kernel_launch(void* const* d_in, const int* in_sizes, int n_in,
                              void* d_out, int out_size, void* d_ws, size_t ws_size,
                              hipStream_t stream) {
  const float* x     = (const float*)d_in[0];
  const float* ln1_g = (const float*)d_in[1];
  const float* ln1_b = (const float*)d_in[2];
  const float* ln2_g = (const float*)d_in[3];
  const float* ln2_b = (const float*)d_in[4];
  const float* Wq    = (const float*)d_in[5];
  const float* bq    = (const float*)d_in[6];
  const float* Wk    = (const float*)d_in[7];
  const float* bk    = (const float*)d_in[8];
  const float* Wv    = (const float*)d_in[9];
  const float* bv    = (const float*)d_in[10];
  const float* W1    = (const float*)d_in[11];
  const float* b1    = (const float*)d_in[12];
  const float* W2    = (const float*)d_in[13];
  const float* b2    = (const float*)d_in[14];
  float* out = (float*)d_out;

  char* p = (char*)d_ws;
  auto alloc = [&](size_t bytes) { char* r = p; p += (bytes + 255) & ~(size_t)255; return r; };
  __hip_bfloat16* wqkv = (__hip_bfloat16*)alloc(3072 * 1024 * 2);
  __hip_bfloat16* w1t  = (__hip_bfloat16*)alloc(4096 * 1024 * 2);
  __hip_bfloat16* w2t  = (__hip_bfloat16*)alloc(1024 * 4096 * 2);
  float*          bqkv = (float*)alloc(3072 * 4);
  __hip_bfloat16* h1   = (__hip_bfloat16*)alloc(4096 * 1024 * 2);
  __hip_bfloat16* Qb   = (__hip_bfloat16*)alloc((size_t)64 * 65536 * 2);  // [64][1024][64]
  __hip_bfloat16* Kb   = (__hip_bfloat16*)alloc((size_t)64 * 65536 * 2);
  __hip_bfloat16* Vt   = (__hip_bfloat16*)alloc((size_t)64 * 65536 * 2);  // [64][64][1024]
  float*          TV   = (float*)alloc((size_t)64 * 8 * 64 * 4);
  float*          yb   = (float*)alloc((size_t)4096 * 1024 * 4);
  __hip_bfloat16* h2   = (__hip_bfloat16*)alloc(4096 * 1024 * 2);
  __hip_bfloat16* G    = (__hip_bfloat16*)alloc((size_t)4096 * 4096 * 2);
  (void)ws_size; (void)in_sizes; (void)n_in; (void)out_size;

  const dim3 b256(256), bt(32, 8);
  k_prep<<<11276, bt, 0, stream>>>(Wq, Wk, Wv, wqkv, W1, w1t, W2, w2t,
                                   bq, bk, bv, bqkv);

  k_ln<<<4096, b256, 0, stream>>>(x, nullptr, ln1_g, ln1_b, h1, nullptr, nullptr);
  k_gemm_qkv<<<dim3(32, 24), dim3(512), 0, stream>>>(h1, wqkv, bqkv, Qb, Kb, Vt);
  k_tailv<<<64, b256, 0, stream>>>(Vt, TV);
  k_attn<<<dim3(8, 64), dim3(512), 0, stream>>>(Qb, Kb, Vt, TV, yb);

  k_ln<<<4096, b256, 0, stream>>>(x, yb, ln2_g, ln2_b, h2, b2, out);
  k_gemm_mlp1<<<dim3(16, 16), dim3(512), 0, stream>>>(h2, w1t, b1, G);
  k_gemm_mlp2<<<dim3(32, 8), dim3(512), 0, stream>>>(G, w2t, out);
}